// Round 1
// baseline (5955.774 us; speedup 1.0000x reference)
//
#include <hip/hip_runtime.h>

// Problem: ShiftAddNet BasicBlock, N=64, C=planes=128, H=W=32, fp32.
// Pipeline: conv1(shift) -> adder1 -> BN1+ReLU -> conv2(shift) -> adder2 -> BN2 + residual + ReLU
// All compute-bound on the adder SAD loops (pure VALU; no MFMA path for |a-w|).

#define NB   64
#define CIN  128
#define HW   32
#define COUT 128
constexpr int PLANE     = HW * HW;        // 1024
constexpr int LDS_ROW   = 35;             // 34 cols padded to 35 (bank-friendly)
constexpr int LDS_PLANE = 34 * LDS_ROW;   // 1190
constexpr int CI_CHUNK  = 4;
constexpr int CO_CHUNK  = 8;
constexpr float INV_SCALE = 1.0f / 32768.0f;

// ---------------------------------------------------------------- shift conv
// out[n,co,h,w] = sum_{ci,kh,kw} round_fixed(in)[n,ci,h-1+kh,w-1+kw] * w[co,ci,kh,kw]
__global__ __launch_bounds__(256) void conv3x3_round(
    const float* __restrict__ in, const float* __restrict__ wgt,
    float* __restrict__ out)
{
    __shared__ float sIn[CI_CHUNK * LDS_PLANE];

    const int bid = blockIdx.x;
    const int n   = bid >> 4;                 // 64 images
    const int co0 = (bid & 15) * CO_CHUNK;    // 16 chunks of 8 channels
    const int tid = threadIdx.x;
    const int r   = tid >> 3;                 // output row 0..31
    const int c0  = (tid & 7) * 4;            // output col base 0..28

    float acc[4][CO_CHUNK];
#pragma unroll
    for (int p = 0; p < 4; ++p)
#pragma unroll
        for (int co = 0; co < CO_CHUNK; ++co) acc[p][co] = 0.0f;

    const float* inN = in + (size_t)n * CIN * PLANE;

    for (int ci0 = 0; ci0 < CIN; ci0 += CI_CHUNK) {
        __syncthreads();
        // stage CI_CHUNK padded 34x34 planes, applying round_fixed
        for (int idx = tid; idx < CI_CHUNK * 1156; idx += 256) {
            int cil = idx / 1156;
            int rem = idx - cil * 1156;
            int rr  = rem / 34;
            int cc  = rem - rr * 34;
            int h = rr - 1, w = cc - 1;
            float v = 0.0f;
            if ((unsigned)h < 32u && (unsigned)w < 32u) {
                v = inN[(ci0 + cil) * PLANE + h * HW + w];
                v = rintf(v * 32768.0f) * INV_SCALE;   // round_fixed (half-even)
            }
            sIn[cil * LDS_PLANE + rr * LDS_ROW + cc] = v;
        }
        __syncthreads();

#pragma unroll
        for (int cil = 0; cil < CI_CHUNK; ++cil) {
            float t[3][6];
            const float* sp = &sIn[cil * LDS_PLANE + r * LDS_ROW + c0];
#pragma unroll
            for (int dh = 0; dh < 3; ++dh)
#pragma unroll
                for (int j = 0; j < 6; ++j)
                    t[dh][j] = sp[dh * LDS_ROW + j];

            const float* wp = wgt + ((size_t)co0 * CIN + (ci0 + cil)) * 9;
#pragma unroll
            for (int co = 0; co < CO_CHUNK; ++co) {
#pragma unroll
                for (int dh = 0; dh < 3; ++dh)
#pragma unroll
                    for (int dw = 0; dw < 3; ++dw) {
                        const float wv = wp[(size_t)co * CIN * 9 + dh * 3 + dw];
#pragma unroll
                        for (int p = 0; p < 4; ++p)
                            acc[p][co] = fmaf(t[dh][p + dw], wv, acc[p][co]);
                    }
            }
        }
    }

    float* outP = out + ((size_t)n * COUT + co0) * PLANE + r * HW + c0;
#pragma unroll
    for (int co = 0; co < CO_CHUNK; ++co) {
        float4 v = make_float4(acc[0][co], acc[1][co], acc[2][co], acc[3][co]);
        *reinterpret_cast<float4*>(&outP[co * PLANE]) = v;
    }
}

// ---------------------------------------------------------------- adder conv
// out[n,co,h,w] = -sum |in[n,ci,h-1+kh,w-1+kw] - w[co,ci,kh,kw]|  (zero-padded)
// also accumulates per-channel sum / sumsq (fp64) for train-mode BN
__global__ __launch_bounds__(256) void adder3x3_stats(
    const float* __restrict__ in, const float* __restrict__ wgt,
    float* __restrict__ out, double* __restrict__ ssum, double* __restrict__ ssq)
{
    __shared__ float sIn[CI_CHUNK * LDS_PLANE];

    const int bid = blockIdx.x;
    const int n   = bid >> 4;
    const int co0 = (bid & 15) * CO_CHUNK;
    const int tid = threadIdx.x;
    const int r   = tid >> 3;
    const int c0  = (tid & 7) * 4;

    float acc[4][CO_CHUNK];
#pragma unroll
    for (int p = 0; p < 4; ++p)
#pragma unroll
        for (int co = 0; co < CO_CHUNK; ++co) acc[p][co] = 0.0f;

    const float* inN = in + (size_t)n * CIN * PLANE;

    for (int ci0 = 0; ci0 < CIN; ci0 += CI_CHUNK) {
        __syncthreads();
        for (int idx = tid; idx < CI_CHUNK * 1156; idx += 256) {
            int cil = idx / 1156;
            int rem = idx - cil * 1156;
            int rr  = rem / 34;
            int cc  = rem - rr * 34;
            int h = rr - 1, w = cc - 1;
            float v = 0.0f;
            if ((unsigned)h < 32u && (unsigned)w < 32u)
                v = inN[(ci0 + cil) * PLANE + h * HW + w];
            sIn[cil * LDS_PLANE + rr * LDS_ROW + cc] = v;
        }
        __syncthreads();

#pragma unroll
        for (int cil = 0; cil < CI_CHUNK; ++cil) {
            float t[3][6];
            const float* sp = &sIn[cil * LDS_PLANE + r * LDS_ROW + c0];
#pragma unroll
            for (int dh = 0; dh < 3; ++dh)
#pragma unroll
                for (int j = 0; j < 6; ++j)
                    t[dh][j] = sp[dh * LDS_ROW + j];

            const float* wp = wgt + ((size_t)co0 * CIN + (ci0 + cil)) * 9;
#pragma unroll
            for (int co = 0; co < CO_CHUNK; ++co) {
#pragma unroll
                for (int dh = 0; dh < 3; ++dh)
#pragma unroll
                    for (int dw = 0; dw < 3; ++dw) {
                        const float wv = wp[(size_t)co * CIN * 9 + dh * 3 + dw];
#pragma unroll
                        for (int p = 0; p < 4; ++p)
                            acc[p][co] += fabsf(t[dh][p + dw] - wv);  // v_sub + v_add(|.|)
                    }
            }
        }
    }

    const int lane = tid & 63;
    float* outP = out + ((size_t)n * COUT + co0) * PLANE + r * HW + c0;
#pragma unroll
    for (int co = 0; co < CO_CHUNK; ++co) {
        float y0 = -acc[0][co], y1 = -acc[1][co], y2 = -acc[2][co], y3 = -acc[3][co];
        *reinterpret_cast<float4*>(&outP[co * PLANE]) = make_float4(y0, y1, y2, y3);
        float s = (y0 + y1) + (y2 + y3);
        float q = fmaf(y0, y0, y1 * y1) + fmaf(y2, y2, y3 * y3);
#pragma unroll
        for (int m = 32; m > 0; m >>= 1) {
            s += __shfl_xor(s, m, 64);
            q += __shfl_xor(q, m, 64);
        }
        if (lane == 0) {
            atomicAdd(&ssum[co0 + co], (double)s);
            atomicAdd(&ssq [co0 + co], (double)q);
        }
    }
}

// ---------------------------------------------------------------- BN helpers
__global__ void zero_stats(double* st) {
    int i = threadIdx.x;
    st[i] = 0.0; st[i + 256] = 0.0;   // 512 doubles total
}

__global__ void finalize_bn(const double* __restrict__ ssum, const double* __restrict__ ssq,
                            const float* __restrict__ gamma, const float* __restrict__ beta,
                            float* __restrict__ scale, float* __restrict__ bias)
{
    int c = threadIdx.x;  // 128
    const double cnt = (double)NB * PLANE;  // 65536
    double m   = ssum[c] / cnt;
    double var = ssq[c] / cnt - m * m;
    double rstd = 1.0 / sqrt(var + 1e-5);
    float sc = (float)((double)gamma[c] * rstd);
    scale[c] = sc;
    bias[c]  = beta[c] - (float)(m) * sc;
}

__global__ __launch_bounds__(256) void bn_relu(
    const float4* __restrict__ in, const float* __restrict__ scale,
    const float* __restrict__ bias, float4* __restrict__ out)
{
    int i = blockIdx.x * 256 + threadIdx.x;       // total4 = 2097152 exact
    int c = (i >> 8) & 127;                        // 256 float4 per plane
    float sc = scale[c], bs = bias[c];
    float4 v = in[i];
    v.x = fmaxf(fmaf(v.x, sc, bs), 0.0f);
    v.y = fmaxf(fmaf(v.y, sc, bs), 0.0f);
    v.z = fmaxf(fmaf(v.z, sc, bs), 0.0f);
    v.w = fmaxf(fmaf(v.w, sc, bs), 0.0f);
    out[i] = v;
}

__global__ __launch_bounds__(256) void bn_add_relu(
    float4* __restrict__ io, const float4* __restrict__ res,
    const float* __restrict__ scale, const float* __restrict__ bias)
{
    int i = blockIdx.x * 256 + threadIdx.x;
    int c = (i >> 8) & 127;
    float sc = scale[c], bs = bias[c];
    float4 v = io[i];
    float4 x = res[i];
    v.x = fmaxf(fmaf(v.x, sc, bs) + x.x, 0.0f);
    v.y = fmaxf(fmaf(v.y, sc, bs) + x.y, 0.0f);
    v.z = fmaxf(fmaf(v.z, sc, bs) + x.z, 0.0f);
    v.w = fmaxf(fmaf(v.w, sc, bs) + x.w, 0.0f);
    io[i] = v;
}

// ---------------------------------------------------------------- launch
extern "C" void kernel_launch(void* const* d_in, const int* in_sizes, int n_in,
                              void* d_out, int out_size, void* d_ws, size_t ws_size,
                              hipStream_t stream)
{
    const float* x    = (const float*)d_in[0];
    const float* wS1  = (const float*)d_in[1];
    const float* wA1  = (const float*)d_in[2];
    const float* g1   = (const float*)d_in[3];
    const float* b1   = (const float*)d_in[4];
    const float* wS2  = (const float*)d_in[5];
    const float* wA2  = (const float*)d_in[6];
    const float* g2   = (const float*)d_in[7];
    const float* b2   = (const float*)d_in[8];
    float* outp = (float*)d_out;

    char* ws = (char*)d_ws;
    float*  bufA = (float*)ws;                                  // 33,554,432 B
    double* st   = (double*)(ws + (size_t)33554432);            // 512 doubles
    float*  sb   = (float*)(st + 512);                          // 512 floats (scale/bias x2)

    double* s1 = st,       *q1 = st + 128;
    double* s2 = st + 256, *q2 = st + 384;
    float* sc1 = sb,       *bi1 = sb + 128;
    float* sc2 = sb + 256, *bi2 = sb + 384;

    const int convGrid = NB * (COUT / CO_CHUNK);   // 1024
    const int ewGrid   = (NB * COUT * PLANE / 4) / 256;  // 8192

    zero_stats<<<1, 256, 0, stream>>>(st);

    // conv1: x -> d_out (used as scratch)
    conv3x3_round<<<convGrid, 256, 0, stream>>>(x, wS1, outp);
    // adder1: d_out -> bufA, stats1
    adder3x3_stats<<<convGrid, 256, 0, stream>>>(outp, wA1, bufA, s1, q1);
    finalize_bn<<<1, 128, 0, stream>>>(s1, q1, g1, b1, sc1, bi1);
    // bn1+relu: bufA -> d_out
    bn_relu<<<ewGrid, 256, 0, stream>>>((const float4*)bufA, sc1, bi1, (float4*)outp);
    // conv2: d_out -> bufA
    conv3x3_round<<<convGrid, 256, 0, stream>>>(outp, wS2, bufA);
    // adder2: bufA -> d_out, stats2
    adder3x3_stats<<<convGrid, 256, 0, stream>>>(bufA, wA2, outp, s2, q2);
    finalize_bn<<<1, 128, 0, stream>>>(s2, q2, g2, b2, sc2, bi2);
    // bn2 + residual + relu, in place on d_out
    bn_add_relu<<<ewGrid, 256, 0, stream>>>((float4*)outp, (const float4*)x, sc2, bi2);
}

// Round 2
// 2842.341 us; speedup vs baseline: 2.0954x; 2.0954x over previous
//
#include <hip/hip_runtime.h>

// ShiftAddNet BasicBlock, N=64, C=planes=128, H=W=32, fp32.
// conv1(shift,rounded-in) -> adder1 -> BN1+ReLU -> conv2(shift,rounded-in) -> adder2 -> BN2+res+ReLU
// Compute-bound on the adder SAD loops (pure VALU). R2: division-free float4
// staging with zero-halo-once LDS layout + double-buffered (load-early/store-late).

#define NB   64
#define CIN  128
#define HW   32
#define COUT 128
constexpr int PLANE   = HW * HW;      // 1024
constexpr int LROW    = 36;           // row stride (floats): 16B-aligned rows
constexpr int LPLANE  = 34 * LROW;    // 1224 floats per padded plane
constexpr int CI_CHUNK = 4;
constexpr int CO_CHUNK = 8;
constexpr int GUARD   = 8;            // zeroed guard so [base-1] reads are 0
constexpr int LDS_TOT = 2 * CI_CHUNK * LPLANE + GUARD;   // 9800 floats = 39.2 KB
constexpr float INV_SCALE = 1.0f / 32768.0f;

// Shared inner loop: ROUND=1 applies fixed-point rounding + multiply (conv),
// ROUND=0 does |a-w| accumulate (adder).
template <int DO_ROUND>
__device__ __forceinline__ void stage_regs(const float* __restrict__ inN,
                                           int ci0, int cil, int lane, float4 nv[4])
{
    const float4* g = (const float4*)(inN + (size_t)(ci0 + cil) * PLANE);
#pragma unroll
    for (int i = 0; i < 4; ++i) {
        float4 v = g[lane + 64 * i];
        if (DO_ROUND) {
            v.x = rintf(v.x * 32768.0f) * INV_SCALE;
            v.y = rintf(v.y * 32768.0f) * INV_SCALE;
            v.z = rintf(v.z * 32768.0f) * INV_SCALE;
            v.w = rintf(v.w * 32768.0f) * INV_SCALE;
        }
        nv[i] = v;
    }
}

__device__ __forceinline__ void stage_write(float* __restrict__ wb, int lane,
                                            const float4 nv[4])
{
#pragma unroll
    for (int i = 0; i < 4; ++i) {
        int idx = lane + 64 * i;                 // 0..255
        int rr  = idx >> 3;                      // 0..31
        int cc  = (idx & 7) * 4;                 // 0..28
        *reinterpret_cast<float4*>(&wb[(rr + 1) * LROW + cc]) = nv[i];
    }
}

// ---------------------------------------------------------------- shift conv
__global__ __launch_bounds__(256) void conv3x3_round(
    const float* __restrict__ in, const float* __restrict__ wgt,
    float* __restrict__ out)
{
    __shared__ float sIn[LDS_TOT];
    float* sG = sIn + GUARD;

    const int bid = blockIdx.x;
    const int n   = bid >> 4;
    const int co0 = (bid & 15) * CO_CHUNK;
    const int tid = threadIdx.x;
    const int r   = tid >> 3;
    const int c0  = (tid & 7) * 4;
    const int cil = tid >> 6;        // 0..3 staging plane
    const int lane = tid & 63;

    float acc[4][CO_CHUNK];
#pragma unroll
    for (int p = 0; p < 4; ++p)
#pragma unroll
        for (int co = 0; co < CO_CHUNK; ++co) acc[p][co] = 0.0f;

    const float* inN = in + (size_t)n * CIN * PLANE;

    // zero all LDS (pads/guard stay zero forever)
    for (int i = tid; i < LDS_TOT; i += 256) sIn[i] = 0.0f;
    float4 v0[4];
    stage_regs<1>(inN, 0, cil, lane, v0);
    __syncthreads();                       // zeroing visible
    stage_write(sG + cil * LPLANE, lane, v0);

    int cur = 0;
    for (int ci0 = 0; ci0 < CIN; ci0 += CI_CHUNK) {
        float4 nv[4];
        const bool more = (ci0 + CI_CHUNK) < CIN;
        if (more) stage_regs<1>(inN, ci0 + CI_CHUNK, cil, lane, nv);
        __syncthreads();                   // current buffer staged

        const float* sb = sG + cur * CI_CHUNK * LPLANE;
#pragma unroll
        for (int cc = 0; cc < CI_CHUNK; ++cc) {
            float t[3][6];
            const float* sp = sb + cc * LPLANE + r * LROW + (c0 - 1);
#pragma unroll
            for (int dh = 0; dh < 3; ++dh)
#pragma unroll
                for (int j = 0; j < 6; ++j)
                    t[dh][j] = sp[dh * LROW + j];

            const float* wp = wgt + ((size_t)co0 * CIN + (ci0 + cc)) * 9;
#pragma unroll
            for (int co = 0; co < CO_CHUNK; ++co)
#pragma unroll
                for (int dh = 0; dh < 3; ++dh)
#pragma unroll
                    for (int dw = 0; dw < 3; ++dw) {
                        const float wv = wp[(size_t)co * CIN * 9 + dh * 3 + dw];
#pragma unroll
                        for (int p = 0; p < 4; ++p)
                            acc[p][co] = fmaf(t[dh][p + dw], wv, acc[p][co]);
                    }
        }
        if (more) stage_write(sG + (cur ^ 1) * CI_CHUNK * LPLANE + cil * LPLANE, lane, nv);
        cur ^= 1;
    }

    float* outP = out + ((size_t)n * COUT + co0) * PLANE + r * HW + c0;
#pragma unroll
    for (int co = 0; co < CO_CHUNK; ++co)
        *reinterpret_cast<float4*>(&outP[co * PLANE]) =
            make_float4(acc[0][co], acc[1][co], acc[2][co], acc[3][co]);
}

// ---------------------------------------------------------------- adder conv
__global__ __launch_bounds__(256) void adder3x3_stats(
    const float* __restrict__ in, const float* __restrict__ wgt,
    float* __restrict__ out, double* __restrict__ ssum, double* __restrict__ ssq)
{
    __shared__ float sIn[LDS_TOT];
    float* sG = sIn + GUARD;

    const int bid = blockIdx.x;
    const int n   = bid >> 4;
    const int co0 = (bid & 15) * CO_CHUNK;
    const int tid = threadIdx.x;
    const int r   = tid >> 3;
    const int c0  = (tid & 7) * 4;
    const int cil = tid >> 6;
    const int lane = tid & 63;

    float acc[4][CO_CHUNK];
#pragma unroll
    for (int p = 0; p < 4; ++p)
#pragma unroll
        for (int co = 0; co < CO_CHUNK; ++co) acc[p][co] = 0.0f;

    const float* inN = in + (size_t)n * CIN * PLANE;

    for (int i = tid; i < LDS_TOT; i += 256) sIn[i] = 0.0f;
    float4 v0[4];
    stage_regs<0>(inN, 0, cil, lane, v0);
    __syncthreads();
    stage_write(sG + cil * LPLANE, lane, v0);

    int cur = 0;
    for (int ci0 = 0; ci0 < CIN; ci0 += CI_CHUNK) {
        float4 nv[4];
        const bool more = (ci0 + CI_CHUNK) < CIN;
        if (more) stage_regs<0>(inN, ci0 + CI_CHUNK, cil, lane, nv);
        __syncthreads();

        const float* sb = sG + cur * CI_CHUNK * LPLANE;
#pragma unroll
        for (int cc = 0; cc < CI_CHUNK; ++cc) {
            float t[3][6];
            const float* sp = sb + cc * LPLANE + r * LROW + (c0 - 1);
#pragma unroll
            for (int dh = 0; dh < 3; ++dh)
#pragma unroll
                for (int j = 0; j < 6; ++j)
                    t[dh][j] = sp[dh * LROW + j];

            const float* wp = wgt + ((size_t)co0 * CIN + (ci0 + cc)) * 9;
#pragma unroll
            for (int co = 0; co < CO_CHUNK; ++co)
#pragma unroll
                for (int dh = 0; dh < 3; ++dh)
#pragma unroll
                    for (int dw = 0; dw < 3; ++dw) {
                        const float wv = wp[(size_t)co * CIN * 9 + dh * 3 + dw];
#pragma unroll
                        for (int p = 0; p < 4; ++p)
                            acc[p][co] += fabsf(t[dh][p + dw] - wv);
                    }
        }
        if (more) stage_write(sG + (cur ^ 1) * CI_CHUNK * LPLANE + cil * LPLANE, lane, nv);
        cur ^= 1;
    }

    float* outP = out + ((size_t)n * COUT + co0) * PLANE + r * HW + c0;
#pragma unroll
    for (int co = 0; co < CO_CHUNK; ++co) {
        float y0 = -acc[0][co], y1 = -acc[1][co], y2 = -acc[2][co], y3 = -acc[3][co];
        *reinterpret_cast<float4*>(&outP[co * PLANE]) = make_float4(y0, y1, y2, y3);
        float s = (y0 + y1) + (y2 + y3);
        float q = fmaf(y0, y0, y1 * y1) + fmaf(y2, y2, y3 * y3);
#pragma unroll
        for (int m = 32; m > 0; m >>= 1) {
            s += __shfl_xor(s, m, 64);
            q += __shfl_xor(q, m, 64);
        }
        if (lane == 0) {
            atomicAdd(&ssum[co0 + co], (double)s);
            atomicAdd(&ssq [co0 + co], (double)q);
        }
    }
}

// ---------------------------------------------------------------- BN helpers
__global__ void zero_stats(double* st) {
    int i = threadIdx.x;
    st[i] = 0.0; st[i + 256] = 0.0;
}

__global__ void finalize_bn(const double* __restrict__ ssum, const double* __restrict__ ssq,
                            const float* __restrict__ gamma, const float* __restrict__ beta,
                            float* __restrict__ scale, float* __restrict__ bias)
{
    int c = threadIdx.x;  // 128
    const double cnt = (double)NB * PLANE;
    double m   = ssum[c] / cnt;
    double var = ssq[c] / cnt - m * m;
    double rstd = 1.0 / sqrt(var + 1e-5);
    float sc = (float)((double)gamma[c] * rstd);
    scale[c] = sc;
    bias[c]  = beta[c] - (float)m * sc;
}

__global__ __launch_bounds__(256) void bn_relu(
    const float4* __restrict__ in, const float* __restrict__ scale,
    const float* __restrict__ bias, float4* __restrict__ out)
{
    int i = blockIdx.x * 256 + threadIdx.x;
    int c = (i >> 8) & 127;
    float sc = scale[c], bs = bias[c];
    float4 v = in[i];
    v.x = fmaxf(fmaf(v.x, sc, bs), 0.0f);
    v.y = fmaxf(fmaf(v.y, sc, bs), 0.0f);
    v.z = fmaxf(fmaf(v.z, sc, bs), 0.0f);
    v.w = fmaxf(fmaf(v.w, sc, bs), 0.0f);
    out[i] = v;
}

__global__ __launch_bounds__(256) void bn_add_relu(
    float4* __restrict__ io, const float4* __restrict__ res,
    const float* __restrict__ scale, const float* __restrict__ bias)
{
    int i = blockIdx.x * 256 + threadIdx.x;
    int c = (i >> 8) & 127;
    float sc = scale[c], bs = bias[c];
    float4 v = io[i];
    float4 x = res[i];
    v.x = fmaxf(fmaf(v.x, sc, bs) + x.x, 0.0f);
    v.y = fmaxf(fmaf(v.y, sc, bs) + x.y, 0.0f);
    v.z = fmaxf(fmaf(v.z, sc, bs) + x.z, 0.0f);
    v.w = fmaxf(fmaf(v.w, sc, bs) + x.w, 0.0f);
    io[i] = v;
}

// ---------------------------------------------------------------- launch
extern "C" void kernel_launch(void* const* d_in, const int* in_sizes, int n_in,
                              void* d_out, int out_size, void* d_ws, size_t ws_size,
                              hipStream_t stream)
{
    const float* x    = (const float*)d_in[0];
    const float* wS1  = (const float*)d_in[1];
    const float* wA1  = (const float*)d_in[2];
    const float* g1   = (const float*)d_in[3];
    const float* b1   = (const float*)d_in[4];
    const float* wS2  = (const float*)d_in[5];
    const float* wA2  = (const float*)d_in[6];
    const float* g2   = (const float*)d_in[7];
    const float* b2   = (const float*)d_in[8];
    float* outp = (float*)d_out;

    char* ws = (char*)d_ws;
    float*  bufA = (float*)ws;                                  // 32 MiB
    double* st   = (double*)(ws + (size_t)33554432);            // 512 doubles
    float*  sb   = (float*)(st + 512);                          // 512 floats

    double* s1 = st,       *q1 = st + 128;
    double* s2 = st + 256, *q2 = st + 384;
    float* sc1 = sb,       *bi1 = sb + 128;
    float* sc2 = sb + 256, *bi2 = sb + 384;

    const int convGrid = NB * (COUT / CO_CHUNK);          // 1024
    const int ewGrid   = (NB * COUT * PLANE / 4) / 256;   // 8192

    zero_stats<<<1, 256, 0, stream>>>(st);

    conv3x3_round<<<convGrid, 256, 0, stream>>>(x, wS1, outp);
    adder3x3_stats<<<convGrid, 256, 0, stream>>>(outp, wA1, bufA, s1, q1);
    finalize_bn<<<1, 128, 0, stream>>>(s1, q1, g1, b1, sc1, bi1);
    bn_relu<<<ewGrid, 256, 0, stream>>>((const float4*)bufA, sc1, bi1, (float4*)outp);
    conv3x3_round<<<convGrid, 256, 0, stream>>>(outp, wS2, bufA);
    adder3x3_stats<<<convGrid, 256, 0, stream>>>(bufA, wA2, outp, s2, q2);
    finalize_bn<<<1, 128, 0, stream>>>(s2, q2, g2, b2, sc2, bi2);
    bn_add_relu<<<ewGrid, 256, 0, stream>>>((float4*)outp, (const float4*)x, sc2, bi2);
}

// Round 3
// 2171.350 us; speedup vs baseline: 2.7429x; 1.3090x over previous
//
#include <hip/hip_runtime.h>

// ShiftAddNet BasicBlock, N=64, C=planes=128, H=W=32, fp32.
// R3: packed [34][32] LDS planes (zero guard rows), global_load_lds width-16
// async staging, aligned ds_read_b128 + DPP horizontal halo, 4 blocks/CU.

#define NB   64
#define CIN  128
#define HW   32
#define COUT 128
constexpr int PLANE    = HW * HW;        // 1024
constexpr int CI_CHUNK = 4;
constexpr int CO_CHUNK = 8;
constexpr int LPLANE   = 34 * 32;        // guard row + 32 rows + guard row
constexpr int LDS_TOT  = 2 * CI_CHUNK * LPLANE;   // 8704 floats = 34816 B
constexpr float FSCALE    = 32768.0f;
constexpr float INV_SCALE = 1.0f / 32768.0f;

#define GLOBAL_AS __attribute__((address_space(1)))
#define LDS_AS    __attribute__((address_space(3)))

__device__ __forceinline__ void gload_lds16(const float* g, float* l) {
    __builtin_amdgcn_global_load_lds((const GLOBAL_AS void*)g, (LDS_AS void*)l,
                                     16, 0, 0);
}

// lane n <- lane n-1 (row_shr:1); OOB lanes get 0 (bound_ctrl)
__device__ __forceinline__ float dpp_prev(float x) {
    return __int_as_float(__builtin_amdgcn_update_dpp(
        0, __float_as_int(x), 0x111, 0xF, 0xF, true));
}
// lane n <- lane n+1 (row_shl:1)
__device__ __forceinline__ float dpp_next(float x) {
    return __int_as_float(__builtin_amdgcn_update_dpp(
        0, __float_as_int(x), 0x101, 0xF, 0xF, true));
}

// stage one 32x32 plane into LDS center rows (async, 4 x 1KB issues)
__device__ __forceinline__ void stage_plane(const float* src, float* lplane, int lane) {
#pragma unroll
    for (int i = 0; i < 4; ++i)
        gload_lds16(src + i * 256 + lane * 4, lplane + 32 + i * 256);
}

template <int DO_ROUND>
__device__ __forceinline__ void load_window(const float* sp, bool cz, bool c7,
                                            float w[6]) {
    float4 q = *reinterpret_cast<const float4*>(sp);   // aligned ds_read_b128
    if (DO_ROUND) {
        q.x = rintf(q.x * FSCALE) * INV_SCALE;
        q.y = rintf(q.y * FSCALE) * INV_SCALE;
        q.z = rintf(q.z * FSCALE) * INV_SCALE;
        q.w = rintf(q.w * FSCALE) * INV_SCALE;
    }
    float lf = dpp_prev(q.w);
    float rt = dpp_next(q.x);
    w[0] = cz ? 0.0f : lf;
    w[1] = q.x; w[2] = q.y; w[3] = q.z; w[4] = q.w;
    w[5] = c7 ? 0.0f : rt;
}

template <int DO_ROUND, int IS_ADDER>
__global__ __launch_bounds__(256, 4) void block_conv(
    const float* __restrict__ in, const float* __restrict__ wgt,
    float* __restrict__ out, double* __restrict__ ssum, double* __restrict__ ssq)
{
    __shared__ __align__(16) float sIn[LDS_TOT];

    const int tid  = threadIdx.x;
    const int lane = tid & 63;
    const int wid  = tid >> 6;               // wave id 0..3: stages plane wid
    const int bid  = blockIdx.x;
    const int n    = bid >> 4;
    const int co0  = (bid & 15) * CO_CHUNK;
    const int r    = tid >> 3;               // 0..31
    const int c    = tid & 7;
    const int c0   = c * 4;
    const bool cz  = (c == 0), c7 = (c == 7);

    float acc[4][CO_CHUNK];
#pragma unroll
    for (int p = 0; p < 4; ++p)
#pragma unroll
        for (int co = 0; co < CO_CHUNK; ++co) acc[p][co] = 0.0f;

    const float* inN = in + (size_t)n * CIN * PLANE;

    // zero guard rows of all 8 plane slots (64 guard floats each)
    for (int idx = tid; idx < 512; idx += 256) {
        int slot = idx >> 6, wq = idx & 63;
        sIn[slot * LPLANE + (wq < 32 ? wq : 1024 + wq)] = 0.0f;
    }
    stage_plane(inN + wid * PLANE, sIn + wid * LPLANE, lane);
    __syncthreads();

    int cur = 0;
    for (int ci0 = 0; ci0 < CIN; ci0 += CI_CHUNK) {
        if (ci0 + CI_CHUNK < CIN)
            stage_plane(inN + (size_t)(ci0 + CI_CHUNK + wid) * PLANE,
                        sIn + ((cur ^ 1) * CI_CHUNK + wid) * LPLANE, lane);

        const float* sb = sIn + cur * CI_CHUNK * LPLANE;
#pragma unroll
        for (int cc = 0; cc < CI_CHUNK; ++cc) {
            float w[3][6];
#pragma unroll
            for (int dh = 0; dh < 3; ++dh)
                load_window<DO_ROUND>(sb + cc * LPLANE + (r + dh) * 32 + c0,
                                      cz, c7, w[dh]);

            const float* wp = wgt + ((size_t)co0 * CIN + (ci0 + cc)) * 9;
#pragma unroll
            for (int co = 0; co < CO_CHUNK; ++co)
#pragma unroll
                for (int dh = 0; dh < 3; ++dh)
#pragma unroll
                    for (int dw = 0; dw < 3; ++dw) {
                        const float wvv = wp[(size_t)co * CIN * 9 + dh * 3 + dw];
#pragma unroll
                        for (int p = 0; p < 4; ++p) {
                            if (IS_ADDER)
                                acc[p][co] += fabsf(w[dh][p + dw] - wvv);
                            else
                                acc[p][co] = fmaf(w[dh][p + dw], wvv, acc[p][co]);
                        }
                    }
        }
        __syncthreads();
        cur ^= 1;
    }

    float* outP = out + ((size_t)n * COUT + co0) * PLANE + r * HW + c0;
    if (IS_ADDER) {
#pragma unroll
        for (int co = 0; co < CO_CHUNK; ++co) {
            float y0 = -acc[0][co], y1 = -acc[1][co];
            float y2 = -acc[2][co], y3 = -acc[3][co];
            *reinterpret_cast<float4*>(&outP[co * PLANE]) =
                make_float4(y0, y1, y2, y3);
            float s = (y0 + y1) + (y2 + y3);
            float q = fmaf(y0, y0, y1 * y1) + fmaf(y2, y2, y3 * y3);
#pragma unroll
            for (int m = 32; m > 0; m >>= 1) {
                s += __shfl_xor(s, m, 64);
                q += __shfl_xor(q, m, 64);
            }
            if (lane == 0) {
                atomicAdd(&ssum[co0 + co], (double)s);
                atomicAdd(&ssq [co0 + co], (double)q);
            }
        }
    } else {
#pragma unroll
        for (int co = 0; co < CO_CHUNK; ++co)
            *reinterpret_cast<float4*>(&outP[co * PLANE]) =
                make_float4(acc[0][co], acc[1][co], acc[2][co], acc[3][co]);
    }
}

// ---------------------------------------------------------------- BN helpers
__global__ void zero_stats(double* st) {
    int i = threadIdx.x;
    st[i] = 0.0; st[i + 256] = 0.0;
}

__global__ void finalize_bn(const double* __restrict__ ssum, const double* __restrict__ ssq,
                            const float* __restrict__ gamma, const float* __restrict__ beta,
                            float* __restrict__ scale, float* __restrict__ bias)
{
    int c = threadIdx.x;  // 128
    const double cnt = (double)NB * PLANE;
    double m   = ssum[c] / cnt;
    double var = ssq[c] / cnt - m * m;
    double rstd = 1.0 / sqrt(var + 1e-5);
    float sc = (float)((double)gamma[c] * rstd);
    scale[c] = sc;
    bias[c]  = beta[c] - (float)m * sc;
}

__global__ __launch_bounds__(256) void bn_relu(
    const float4* __restrict__ in, const float* __restrict__ scale,
    const float* __restrict__ bias, float4* __restrict__ out)
{
    int i = blockIdx.x * 256 + threadIdx.x;
    int c = (i >> 8) & 127;
    float sc = scale[c], bs = bias[c];
    float4 v = in[i];
    v.x = fmaxf(fmaf(v.x, sc, bs), 0.0f);
    v.y = fmaxf(fmaf(v.y, sc, bs), 0.0f);
    v.z = fmaxf(fmaf(v.z, sc, bs), 0.0f);
    v.w = fmaxf(fmaf(v.w, sc, bs), 0.0f);
    out[i] = v;
}

__global__ __launch_bounds__(256) void bn_add_relu(
    float4* __restrict__ io, const float4* __restrict__ res,
    const float* __restrict__ scale, const float* __restrict__ bias)
{
    int i = blockIdx.x * 256 + threadIdx.x;
    int c = (i >> 8) & 127;
    float sc = scale[c], bs = bias[c];
    float4 v = io[i];
    float4 x = res[i];
    v.x = fmaxf(fmaf(v.x, sc, bs) + x.x, 0.0f);
    v.y = fmaxf(fmaf(v.y, sc, bs) + x.y, 0.0f);
    v.z = fmaxf(fmaf(v.z, sc, bs) + x.z, 0.0f);
    v.w = fmaxf(fmaf(v.w, sc, bs) + x.w, 0.0f);
    io[i] = v;
}

// ---------------------------------------------------------------- launch
extern "C" void kernel_launch(void* const* d_in, const int* in_sizes, int n_in,
                              void* d_out, int out_size, void* d_ws, size_t ws_size,
                              hipStream_t stream)
{
    const float* x    = (const float*)d_in[0];
    const float* wS1  = (const float*)d_in[1];
    const float* wA1  = (const float*)d_in[2];
    const float* g1   = (const float*)d_in[3];
    const float* b1   = (const float*)d_in[4];
    const float* wS2  = (const float*)d_in[5];
    const float* wA2  = (const float*)d_in[6];
    const float* g2   = (const float*)d_in[7];
    const float* b2   = (const float*)d_in[8];
    float* outp = (float*)d_out;

    char* ws = (char*)d_ws;
    float*  bufA = (float*)ws;                                  // 32 MiB
    double* st   = (double*)(ws + (size_t)33554432);            // 512 doubles
    float*  sb   = (float*)(st + 512);                          // 512 floats

    double* s1 = st,       *q1 = st + 128;
    double* s2 = st + 256, *q2 = st + 384;
    float* sc1 = sb,       *bi1 = sb + 128;
    float* sc2 = sb + 256, *bi2 = sb + 384;

    const int convGrid = NB * (COUT / CO_CHUNK);          // 1024
    const int ewGrid   = (NB * COUT * PLANE / 4) / 256;   // 8192

    zero_stats<<<1, 256, 0, stream>>>(st);

    block_conv<1, 0><<<convGrid, 256, 0, stream>>>(x, wS1, outp, nullptr, nullptr);
    block_conv<0, 1><<<convGrid, 256, 0, stream>>>(outp, wA1, bufA, s1, q1);
    finalize_bn<<<1, 128, 0, stream>>>(s1, q1, g1, b1, sc1, bi1);
    bn_relu<<<ewGrid, 256, 0, stream>>>((const float4*)bufA, sc1, bi1, (float4*)outp);
    block_conv<1, 0><<<convGrid, 256, 0, stream>>>(outp, wS2, bufA, nullptr, nullptr);
    block_conv<0, 1><<<convGrid, 256, 0, stream>>>(bufA, wA2, outp, s2, q2);
    finalize_bn<<<1, 128, 0, stream>>>(s2, q2, g2, b2, sc2, bi2);
    bn_add_relu<<<ewGrid, 256, 0, stream>>>((float4*)outp, (const float4*)x, sc2, bi2);
}

// Round 4
// 2141.043 us; speedup vs baseline: 2.7817x; 1.0142x over previous
//
#include <hip/hip_runtime.h>

// ShiftAddNet BasicBlock, N=64, C=planes=128, H=W=32, fp32.
// R4: R3 structure (packed [34][32] LDS planes, global_load_lds width-16,
// ds_read_b128 + DPP halo) with the spill fixed (launch_bounds(256,2)) and
// T1 XCD-aware block swizzle (all co-chunks of an image on one XCD's L2).

#define NB   64
#define CIN  128
#define HW   32
#define COUT 128
constexpr int PLANE    = HW * HW;        // 1024
constexpr int CI_CHUNK = 4;
constexpr int CO_CHUNK = 8;
constexpr int LPLANE   = 34 * 32;        // guard row + 32 rows + guard row
constexpr int LDS_TOT  = 2 * CI_CHUNK * LPLANE;   // 8704 floats = 34816 B
constexpr float FSCALE    = 32768.0f;
constexpr float INV_SCALE = 1.0f / 32768.0f;

#define GLOBAL_AS __attribute__((address_space(1)))
#define LDS_AS    __attribute__((address_space(3)))

__device__ __forceinline__ void gload_lds16(const float* g, float* l) {
    __builtin_amdgcn_global_load_lds((const GLOBAL_AS void*)g, (LDS_AS void*)l,
                                     16, 0, 0);
}

// lane n <- lane n-1 (row_shr:1); boundary lanes get 0 (bound_ctrl)
__device__ __forceinline__ float dpp_prev(float x) {
    return __int_as_float(__builtin_amdgcn_update_dpp(
        0, __float_as_int(x), 0x111, 0xF, 0xF, true));
}
// lane n <- lane n+1 (row_shl:1)
__device__ __forceinline__ float dpp_next(float x) {
    return __int_as_float(__builtin_amdgcn_update_dpp(
        0, __float_as_int(x), 0x101, 0xF, 0xF, true));
}

// stage one 32x32 plane into LDS center rows (async, 4 x 1KB issues)
__device__ __forceinline__ void stage_plane(const float* src, float* lplane, int lane) {
#pragma unroll
    for (int i = 0; i < 4; ++i)
        gload_lds16(src + i * 256 + lane * 4, lplane + 32 + i * 256);
}

template <int DO_ROUND>
__device__ __forceinline__ void load_window(const float* sp, bool cz, bool c7,
                                            float w[6]) {
    float4 q = *reinterpret_cast<const float4*>(sp);   // aligned ds_read_b128
    if (DO_ROUND) {
        q.x = rintf(q.x * FSCALE) * INV_SCALE;
        q.y = rintf(q.y * FSCALE) * INV_SCALE;
        q.z = rintf(q.z * FSCALE) * INV_SCALE;
        q.w = rintf(q.w * FSCALE) * INV_SCALE;
    }
    float lf = dpp_prev(q.w);
    float rt = dpp_next(q.x);
    w[0] = cz ? 0.0f : lf;
    w[1] = q.x; w[2] = q.y; w[3] = q.z; w[4] = q.w;
    w[5] = c7 ? 0.0f : rt;
}

template <int DO_ROUND, int IS_ADDER>
__global__ __launch_bounds__(256, 2) void block_conv(
    const float* __restrict__ in, const float* __restrict__ wgt,
    float* __restrict__ out, double* __restrict__ ssum, double* __restrict__ ssq)
{
    __shared__ __align__(16) float sIn[LDS_TOT];

    const int tid  = threadIdx.x;
    const int lane = tid & 63;
    const int wid  = tid >> 6;               // wave id 0..3: stages plane wid
    // T1 XCD swizzle: grid 1024, 8 XCDs -> 128 consecutive logical blocks/XCD
    const int bid  = (blockIdx.x & 7) * 128 + (blockIdx.x >> 3);
    const int n    = bid >> 4;
    const int co0  = (bid & 15) * CO_CHUNK;
    const int r    = tid >> 3;               // 0..31
    const int c    = tid & 7;
    const int c0   = c * 4;
    const bool cz  = (c == 0), c7 = (c == 7);

    float acc[4][CO_CHUNK];
#pragma unroll
    for (int p = 0; p < 4; ++p)
#pragma unroll
        for (int co = 0; co < CO_CHUNK; ++co) acc[p][co] = 0.0f;

    const float* inN = in + (size_t)n * CIN * PLANE;

    // zero guard rows of all 8 plane slots (64 guard floats each)
    for (int idx = tid; idx < 512; idx += 256) {
        int slot = idx >> 6, wq = idx & 63;
        sIn[slot * LPLANE + (wq < 32 ? wq : 1024 + wq)] = 0.0f;
    }
    stage_plane(inN + wid * PLANE, sIn + wid * LPLANE, lane);
    __syncthreads();

    int cur = 0;
    for (int ci0 = 0; ci0 < CIN; ci0 += CI_CHUNK) {
        if (ci0 + CI_CHUNK < CIN)
            stage_plane(inN + (size_t)(ci0 + CI_CHUNK + wid) * PLANE,
                        sIn + ((cur ^ 1) * CI_CHUNK + wid) * LPLANE, lane);

        const float* sb = sIn + cur * CI_CHUNK * LPLANE;
#pragma unroll
        for (int cc = 0; cc < CI_CHUNK; ++cc) {
            float w[3][6];
#pragma unroll
            for (int dh = 0; dh < 3; ++dh)
                load_window<DO_ROUND>(sb + cc * LPLANE + (r + dh) * 32 + c0,
                                      cz, c7, w[dh]);

            const float* wp = wgt + ((size_t)co0 * CIN + (ci0 + cc)) * 9;
#pragma unroll
            for (int co = 0; co < CO_CHUNK; ++co)
#pragma unroll
                for (int dh = 0; dh < 3; ++dh)
#pragma unroll
                    for (int dw = 0; dw < 3; ++dw) {
                        const float wvv = wp[(size_t)co * CIN * 9 + dh * 3 + dw];
#pragma unroll
                        for (int p = 0; p < 4; ++p) {
                            if (IS_ADDER)
                                acc[p][co] += fabsf(w[dh][p + dw] - wvv);
                            else
                                acc[p][co] = fmaf(w[dh][p + dw], wvv, acc[p][co]);
                        }
                    }
        }
        __syncthreads();
        cur ^= 1;
    }

    float* outP = out + ((size_t)n * COUT + co0) * PLANE + r * HW + c0;
    if (IS_ADDER) {
#pragma unroll
        for (int co = 0; co < CO_CHUNK; ++co) {
            float y0 = -acc[0][co], y1 = -acc[1][co];
            float y2 = -acc[2][co], y3 = -acc[3][co];
            *reinterpret_cast<float4*>(&outP[co * PLANE]) =
                make_float4(y0, y1, y2, y3);
            float s = (y0 + y1) + (y2 + y3);
            float q = fmaf(y0, y0, y1 * y1) + fmaf(y2, y2, y3 * y3);
#pragma unroll
            for (int m = 32; m > 0; m >>= 1) {
                s += __shfl_xor(s, m, 64);
                q += __shfl_xor(q, m, 64);
            }
            if (lane == 0) {
                atomicAdd(&ssum[co0 + co], (double)s);
                atomicAdd(&ssq [co0 + co], (double)q);
            }
        }
    } else {
#pragma unroll
        for (int co = 0; co < CO_CHUNK; ++co)
            *reinterpret_cast<float4*>(&outP[co * PLANE]) =
                make_float4(acc[0][co], acc[1][co], acc[2][co], acc[3][co]);
    }
}

// ---------------------------------------------------------------- BN helpers
__global__ void zero_stats(double* st) {
    int i = threadIdx.x;
    st[i] = 0.0; st[i + 256] = 0.0;
}

__global__ void finalize_bn(const double* __restrict__ ssum, const double* __restrict__ ssq,
                            const float* __restrict__ gamma, const float* __restrict__ beta,
                            float* __restrict__ scale, float* __restrict__ bias)
{
    int c = threadIdx.x;  // 128
    const double cnt = (double)NB * PLANE;
    double m   = ssum[c] / cnt;
    double var = ssq[c] / cnt - m * m;
    double rstd = 1.0 / sqrt(var + 1e-5);
    float sc = (float)((double)gamma[c] * rstd);
    scale[c] = sc;
    bias[c]  = beta[c] - (float)m * sc;
}

__global__ __launch_bounds__(256) void bn_relu(
    const float4* __restrict__ in, const float* __restrict__ scale,
    const float* __restrict__ bias, float4* __restrict__ out)
{
    int i = blockIdx.x * 256 + threadIdx.x;
    int c = (i >> 8) & 127;
    float sc = scale[c], bs = bias[c];
    float4 v = in[i];
    v.x = fmaxf(fmaf(v.x, sc, bs), 0.0f);
    v.y = fmaxf(fmaf(v.y, sc, bs), 0.0f);
    v.z = fmaxf(fmaf(v.z, sc, bs), 0.0f);
    v.w = fmaxf(fmaf(v.w, sc, bs), 0.0f);
    out[i] = v;
}

__global__ __launch_bounds__(256) void bn_add_relu(
    float4* __restrict__ io, const float4* __restrict__ res,
    const float* __restrict__ scale, const float* __restrict__ bias)
{
    int i = blockIdx.x * 256 + threadIdx.x;
    int c = (i >> 8) & 127;
    float sc = scale[c], bs = bias[c];
    float4 v = io[i];
    float4 x = res[i];
    v.x = fmaxf(fmaf(v.x, sc, bs) + x.x, 0.0f);
    v.y = fmaxf(fmaf(v.y, sc, bs) + x.y, 0.0f);
    v.z = fmaxf(fmaf(v.z, sc, bs) + x.z, 0.0f);
    v.w = fmaxf(fmaf(v.w, sc, bs) + x.w, 0.0f);
    io[i] = v;
}

// ---------------------------------------------------------------- launch
extern "C" void kernel_launch(void* const* d_in, const int* in_sizes, int n_in,
                              void* d_out, int out_size, void* d_ws, size_t ws_size,
                              hipStream_t stream)
{
    const float* x    = (const float*)d_in[0];
    const float* wS1  = (const float*)d_in[1];
    const float* wA1  = (const float*)d_in[2];
    const float* g1   = (const float*)d_in[3];
    const float* b1   = (const float*)d_in[4];
    const float* wS2  = (const float*)d_in[5];
    const float* wA2  = (const float*)d_in[6];
    const float* g2   = (const float*)d_in[7];
    const float* b2   = (const float*)d_in[8];
    float* outp = (float*)d_out;

    char* ws = (char*)d_ws;
    float*  bufA = (float*)ws;                                  // 32 MiB
    double* st   = (double*)(ws + (size_t)33554432);            // 512 doubles
    float*  sb   = (float*)(st + 512);                          // 512 floats

    double* s1 = st,       *q1 = st + 128;
    double* s2 = st + 256, *q2 = st + 384;
    float* sc1 = sb,       *bi1 = sb + 128;
    float* sc2 = sb + 256, *bi2 = sb + 384;

    const int convGrid = NB * (COUT / CO_CHUNK);          // 1024
    const int ewGrid   = (NB * COUT * PLANE / 4) / 256;   // 8192

    zero_stats<<<1, 256, 0, stream>>>(st);

    block_conv<1, 0><<<convGrid, 256, 0, stream>>>(x, wS1, outp, nullptr, nullptr);
    block_conv<0, 1><<<convGrid, 256, 0, stream>>>(outp, wA1, bufA, s1, q1);
    finalize_bn<<<1, 128, 0, stream>>>(s1, q1, g1, b1, sc1, bi1);
    bn_relu<<<ewGrid, 256, 0, stream>>>((const float4*)bufA, sc1, bi1, (float4*)outp);
    block_conv<1, 0><<<convGrid, 256, 0, stream>>>(outp, wS2, bufA, nullptr, nullptr);
    block_conv<0, 1><<<convGrid, 256, 0, stream>>>(bufA, wA2, outp, s2, q2);
    finalize_bn<<<1, 128, 0, stream>>>(s2, q2, g2, b2, sc2, bi2);
    bn_add_relu<<<ewGrid, 256, 0, stream>>>((float4*)outp, (const float4*)x, sc2, bi2);
}

// Round 5
// 1204.696 us; speedup vs baseline: 4.9438x; 1.7772x over previous
//
#include <hip/hip_runtime.h>

// ShiftAddNet BasicBlock, N=64, C=planes=128, H=W=32, fp32.
// R5: adder conv via integer v_sad_u32 (1 VALU op per |a-w| term, was 2-3).
// Activations/weights quantized to 2^-15 grid with +2^19 bias (positive u32,
// no overflow: 1152 * 2^20 < 2^31). Weights pre-quantized by prep kernel when
// ws_size allows (s_load -> SGPR operand), else converted per-use (fallback).
// Conv kept scalar fp32 (isolate the adder change).

#define NB   64
#define CIN  128
#define HW   32
#define COUT 128
constexpr int PLANE    = HW * HW;        // 1024
constexpr int CI_CHUNK = 4;
constexpr int CO_CHUNK = 8;
constexpr int LPLANE   = 34 * 32;        // guard row + 32 rows + guard row
constexpr int LDS_TOT  = 2 * CI_CHUNK * LPLANE;   // 8704 floats = 34816 B
constexpr float FSCALE    = 32768.0f;
constexpr float INV_SCALE = 1.0f / 32768.0f;
// adder fixed-point: a' = (int)(a*32768 + 524288.5)  (always positive)
constexpr float QSCALE = 32768.0f;
constexpr float QBIAS  = 524288.5f;
constexpr int   QZERO  = 524288;         // biased zero (for padding halo)

#define GLOBAL_AS __attribute__((address_space(1)))
#define LDS_AS    __attribute__((address_space(3)))

__device__ __forceinline__ void gload_lds16(const float* g, float* l) {
    __builtin_amdgcn_global_load_lds((const GLOBAL_AS void*)g, (LDS_AS void*)l,
                                     16, 0, 0);
}

// lane n <- lane n-1 (row_shr:1); boundary lanes get 0 (bound_ctrl)
__device__ __forceinline__ float dpp_prev(float x) {
    return __int_as_float(__builtin_amdgcn_update_dpp(
        0, __float_as_int(x), 0x111, 0xF, 0xF, true));
}
__device__ __forceinline__ float dpp_next(float x) {
    return __int_as_float(__builtin_amdgcn_update_dpp(
        0, __float_as_int(x), 0x101, 0xF, 0xF, true));
}
__device__ __forceinline__ int dpp_prev_i(int x) {
    return __builtin_amdgcn_update_dpp(0, x, 0x111, 0xF, 0xF, true);
}
__device__ __forceinline__ int dpp_next_i(int x) {
    return __builtin_amdgcn_update_dpp(0, x, 0x101, 0xF, 0xF, true);
}

// stage one 32x32 plane into LDS center rows (async, 4 x 1KB issues)
__device__ __forceinline__ void stage_plane(const float* src, float* lplane, int lane) {
#pragma unroll
    for (int i = 0; i < 4; ++i)
        gload_lds16(src + i * 256 + lane * 4, lplane + 32 + i * 256);
}

__device__ __forceinline__ int q_act(float a) {
    return (int)fmaf(a, QSCALE, QBIAS);   // v_fma + v_cvt (trunc; arg > 0)
}

// ---------------------------------------------------------------- shift conv
__global__ __launch_bounds__(256, 2) void conv_shift(
    const float* __restrict__ in, const float* __restrict__ wgt,
    float* __restrict__ out)
{
    __shared__ __align__(16) float sIn[LDS_TOT];

    const int tid  = threadIdx.x;
    const int lane = tid & 63;
    const int wid  = tid >> 6;
    const int bid  = (blockIdx.x & 7) * 128 + (blockIdx.x >> 3);  // T1 swizzle
    const int n    = bid >> 4;
    const int co0  = (bid & 15) * CO_CHUNK;
    const int r    = tid >> 3;
    const int c    = tid & 7;
    const int c0   = c * 4;
    const bool cz  = (c == 0), c7 = (c == 7);

    float acc[4][CO_CHUNK];
#pragma unroll
    for (int p = 0; p < 4; ++p)
#pragma unroll
        for (int co = 0; co < CO_CHUNK; ++co) acc[p][co] = 0.0f;

    const float* inN = in + (size_t)n * CIN * PLANE;

    for (int idx = tid; idx < 512; idx += 256) {
        int slot = idx >> 6, wq = idx & 63;
        sIn[slot * LPLANE + (wq < 32 ? wq : 1024 + wq)] = 0.0f;
    }
    stage_plane(inN + wid * PLANE, sIn + wid * LPLANE, lane);
    __syncthreads();

    int cur = 0;
    for (int ci0 = 0; ci0 < CIN; ci0 += CI_CHUNK) {
        if (ci0 + CI_CHUNK < CIN)
            stage_plane(inN + (size_t)(ci0 + CI_CHUNK + wid) * PLANE,
                        sIn + ((cur ^ 1) * CI_CHUNK + wid) * LPLANE, lane);

        const float* sb = sIn + cur * CI_CHUNK * LPLANE;
#pragma unroll
        for (int cc = 0; cc < CI_CHUNK; ++cc) {
            float w[3][6];
#pragma unroll
            for (int dh = 0; dh < 3; ++dh) {
                const float* sp = sb + cc * LPLANE + (r + dh) * 32 + c0;
                float4 q = *reinterpret_cast<const float4*>(sp);
                q.x = rintf(q.x * FSCALE) * INV_SCALE;
                q.y = rintf(q.y * FSCALE) * INV_SCALE;
                q.z = rintf(q.z * FSCALE) * INV_SCALE;
                q.w = rintf(q.w * FSCALE) * INV_SCALE;
                float lf = dpp_prev(q.w);
                float rt = dpp_next(q.x);
                w[dh][0] = cz ? 0.0f : lf;
                w[dh][1] = q.x; w[dh][2] = q.y; w[dh][3] = q.z; w[dh][4] = q.w;
                w[dh][5] = c7 ? 0.0f : rt;
            }

            const float* wp = wgt + ((size_t)co0 * CIN + (ci0 + cc)) * 9;
#pragma unroll
            for (int co = 0; co < CO_CHUNK; ++co)
#pragma unroll
                for (int dh = 0; dh < 3; ++dh)
#pragma unroll
                    for (int dw = 0; dw < 3; ++dw) {
                        const float wvv = wp[(size_t)co * CIN * 9 + dh * 3 + dw];
#pragma unroll
                        for (int p = 0; p < 4; ++p)
                            acc[p][co] = fmaf(w[dh][p + dw], wvv, acc[p][co]);
                    }
        }
        __syncthreads();
        cur ^= 1;
    }

    float* outP = out + ((size_t)n * COUT + co0) * PLANE + r * HW + c0;
#pragma unroll
    for (int co = 0; co < CO_CHUNK; ++co)
        *reinterpret_cast<float4*>(&outP[co * PLANE]) =
            make_float4(acc[0][co], acc[1][co], acc[2][co], acc[3][co]);
}

// ---------------------------------------------------------------- adder conv
// PREQ=1: weights prequantized to int (uniform s_load, "s" asm operand)
// PREQ=0: weights converted per-use in VALU (fallback when ws too small)
template <int PREQ>
__global__ __launch_bounds__(256, 2) void adder_int(
    const float* __restrict__ in, const float* __restrict__ wgtf,
    const int* __restrict__ wgtq,
    float* __restrict__ out, double* __restrict__ ssum, double* __restrict__ ssq)
{
    __shared__ __align__(16) float sIn[LDS_TOT];

    const int tid  = threadIdx.x;
    const int lane = tid & 63;
    const int wid  = tid >> 6;
    const int bid  = (blockIdx.x & 7) * 128 + (blockIdx.x >> 3);
    const int n    = bid >> 4;
    const int co0  = (bid & 15) * CO_CHUNK;
    const int r    = tid >> 3;
    const int c    = tid & 7;
    const int c0   = c * 4;
    const bool cz  = (c == 0), c7 = (c == 7);
    const int zv   = QZERO;                 // biased zero for halo (in VGPR)

    unsigned acc[4][CO_CHUNK];
#pragma unroll
    for (int p = 0; p < 4; ++p)
#pragma unroll
        for (int co = 0; co < CO_CHUNK; ++co) acc[p][co] = 0u;

    const float* inN = in + (size_t)n * CIN * PLANE;

    for (int idx = tid; idx < 512; idx += 256) {
        int slot = idx >> 6, wq = idx & 63;
        sIn[slot * LPLANE + (wq < 32 ? wq : 1024 + wq)] = 0.0f;
    }
    stage_plane(inN + wid * PLANE, sIn + wid * LPLANE, lane);
    __syncthreads();

    int cur = 0;
    for (int ci0 = 0; ci0 < CIN; ci0 += CI_CHUNK) {
        if (ci0 + CI_CHUNK < CIN)
            stage_plane(inN + (size_t)(ci0 + CI_CHUNK + wid) * PLANE,
                        sIn + ((cur ^ 1) * CI_CHUNK + wid) * LPLANE, lane);

        const float* sb = sIn + cur * CI_CHUNK * LPLANE;
#pragma unroll
        for (int cc = 0; cc < CI_CHUNK; ++cc) {
            int wi[3][6];
#pragma unroll
            for (int dh = 0; dh < 3; ++dh) {
                const float* sp = sb + cc * LPLANE + (r + dh) * 32 + c0;
                float4 q = *reinterpret_cast<const float4*>(sp);
                int ax = q_act(q.x), ay = q_act(q.y);
                int az = q_act(q.z), aw = q_act(q.w);
                int lf = dpp_prev_i(aw);
                int rt = dpp_next_i(ax);
                wi[dh][0] = cz ? zv : lf;
                wi[dh][1] = ax; wi[dh][2] = ay; wi[dh][3] = az; wi[dh][4] = aw;
                wi[dh][5] = c7 ? zv : rt;
            }

            const size_t wbase = ((size_t)co0 * CIN + (ci0 + cc)) * 9;
#pragma unroll
            for (int co = 0; co < CO_CHUNK; ++co)
#pragma unroll
                for (int dh = 0; dh < 3; ++dh)
#pragma unroll
                    for (int dw = 0; dw < 3; ++dw) {
                        if (PREQ) {
                            const int wv = wgtq[wbase + (size_t)co * CIN * 9 + dh * 3 + dw];
#pragma unroll
                            for (int p = 0; p < 4; ++p)
                                asm("v_sad_u32 %0, %1, %2, %0"
                                    : "+v"(acc[p][co])
                                    : "v"(wi[dh][p + dw]), "s"(wv));
                        } else {
                            const int wv = (int)fmaf(
                                wgtf[wbase + (size_t)co * CIN * 9 + dh * 3 + dw],
                                QSCALE, QBIAS);
#pragma unroll
                            for (int p = 0; p < 4; ++p)
                                asm("v_sad_u32 %0, %1, %2, %0"
                                    : "+v"(acc[p][co])
                                    : "v"(wi[dh][p + dw]), "v"(wv));
                        }
                    }
        }
        __syncthreads();
        cur ^= 1;
    }

    float* outP = out + ((size_t)n * COUT + co0) * PLANE + r * HW + c0;
#pragma unroll
    for (int co = 0; co < CO_CHUNK; ++co) {
        float y0 = -(float)acc[0][co] * INV_SCALE;
        float y1 = -(float)acc[1][co] * INV_SCALE;
        float y2 = -(float)acc[2][co] * INV_SCALE;
        float y3 = -(float)acc[3][co] * INV_SCALE;
        *reinterpret_cast<float4*>(&outP[co * PLANE]) = make_float4(y0, y1, y2, y3);
        float s = (y0 + y1) + (y2 + y3);
        float q = fmaf(y0, y0, y1 * y1) + fmaf(y2, y2, y3 * y3);
#pragma unroll
        for (int m = 32; m > 0; m >>= 1) {
            s += __shfl_xor(s, m, 64);
            q += __shfl_xor(q, m, 64);
        }
        if (lane == 0) {
            atomicAdd(&ssum[co0 + co], (double)s);
            atomicAdd(&ssq [co0 + co], (double)q);
        }
    }
}

// ---------------------------------------------------------------- prep/BN
__global__ __launch_bounds__(256) void quant_weights(
    const float* __restrict__ w1, const float* __restrict__ w2,
    int* __restrict__ wq)   // wq[0:147456) from w1, [147456:294912) from w2
{
    int i = blockIdx.x * 256 + threadIdx.x;          // grid covers 294912
    float v = (i < 147456) ? w1[i] : w2[i - 147456];
    wq[i] = (int)fmaf(v, QSCALE, QBIAS);
}

__global__ void zero_stats(double* st) {
    int i = threadIdx.x;
    st[i] = 0.0; st[i + 256] = 0.0;
}

__global__ void finalize_bn(const double* __restrict__ ssum, const double* __restrict__ ssq,
                            const float* __restrict__ gamma, const float* __restrict__ beta,
                            float* __restrict__ scale, float* __restrict__ bias)
{
    int c = threadIdx.x;  // 128
    const double cnt = (double)NB * PLANE;
    double m   = ssum[c] / cnt;
    double var = ssq[c] / cnt - m * m;
    double rstd = 1.0 / sqrt(var + 1e-5);
    float sc = (float)((double)gamma[c] * rstd);
    scale[c] = sc;
    bias[c]  = beta[c] - (float)m * sc;
}

__global__ __launch_bounds__(256) void bn_relu(
    const float4* __restrict__ in, const float* __restrict__ scale,
    const float* __restrict__ bias, float4* __restrict__ out)
{
    int i = blockIdx.x * 256 + threadIdx.x;
    int c = (i >> 8) & 127;
    float sc = scale[c], bs = bias[c];
    float4 v = in[i];
    v.x = fmaxf(fmaf(v.x, sc, bs), 0.0f);
    v.y = fmaxf(fmaf(v.y, sc, bs), 0.0f);
    v.z = fmaxf(fmaf(v.z, sc, bs), 0.0f);
    v.w = fmaxf(fmaf(v.w, sc, bs), 0.0f);
    out[i] = v;
}

__global__ __launch_bounds__(256) void bn_add_relu(
    float4* __restrict__ io, const float4* __restrict__ res,
    const float* __restrict__ scale, const float* __restrict__ bias)
{
    int i = blockIdx.x * 256 + threadIdx.x;
    int c = (i >> 8) & 127;
    float sc = scale[c], bs = bias[c];
    float4 v = io[i];
    float4 x = res[i];
    v.x = fmaxf(fmaf(v.x, sc, bs) + x.x, 0.0f);
    v.y = fmaxf(fmaf(v.y, sc, bs) + x.y, 0.0f);
    v.z = fmaxf(fmaf(v.z, sc, bs) + x.z, 0.0f);
    v.w = fmaxf(fmaf(v.w, sc, bs) + x.w, 0.0f);
    io[i] = v;
}

// ---------------------------------------------------------------- launch
extern "C" void kernel_launch(void* const* d_in, const int* in_sizes, int n_in,
                              void* d_out, int out_size, void* d_ws, size_t ws_size,
                              hipStream_t stream)
{
    const float* x    = (const float*)d_in[0];
    const float* wS1  = (const float*)d_in[1];
    const float* wA1  = (const float*)d_in[2];
    const float* g1   = (const float*)d_in[3];
    const float* b1   = (const float*)d_in[4];
    const float* wS2  = (const float*)d_in[5];
    const float* wA2  = (const float*)d_in[6];
    const float* g2   = (const float*)d_in[7];
    const float* b2   = (const float*)d_in[8];
    float* outp = (float*)d_out;

    char* ws = (char*)d_ws;
    float*  bufA = (float*)ws;                                  // 32 MiB
    double* st   = (double*)(ws + (size_t)33554432);            // 512 doubles
    float*  sb   = (float*)(st + 512);                          // 512 floats
    int*    wq   = (int*)(ws + (size_t)33560576);               // 294912 ints
    const size_t ws_needed = 33560576 + (size_t)294912 * 4;     // ~34.7 MB
    const bool preq = ws_size >= ws_needed;

    double* s1 = st,       *q1 = st + 128;
    double* s2 = st + 256, *q2 = st + 384;
    float* sc1 = sb,       *bi1 = sb + 128;
    float* sc2 = sb + 256, *bi2 = sb + 384;

    const int convGrid = NB * (COUT / CO_CHUNK);          // 1024
    const int ewGrid   = (NB * COUT * PLANE / 4) / 256;   // 8192

    zero_stats<<<1, 256, 0, stream>>>(st);
    if (preq)
        quant_weights<<<294912 / 256, 256, 0, stream>>>(wA1, wA2, wq);

    conv_shift<<<convGrid, 256, 0, stream>>>(x, wS1, outp);
    if (preq)
        adder_int<1><<<convGrid, 256, 0, stream>>>(outp, nullptr, wq, bufA, s1, q1);
    else
        adder_int<0><<<convGrid, 256, 0, stream>>>(outp, wA1, nullptr, bufA, s1, q1);
    finalize_bn<<<1, 128, 0, stream>>>(s1, q1, g1, b1, sc1, bi1);
    bn_relu<<<ewGrid, 256, 0, stream>>>((const float4*)bufA, sc1, bi1, (float4*)outp);
    conv_shift<<<convGrid, 256, 0, stream>>>(outp, wS2, bufA);
    if (preq)
        adder_int<1><<<convGrid, 256, 0, stream>>>(bufA, nullptr, wq + 147456, outp, s2, q2);
    else
        adder_int<0><<<convGrid, 256, 0, stream>>>(bufA, wA2, nullptr, outp, s2, q2);
    finalize_bn<<<1, 128, 0, stream>>>(s2, q2, g2, b2, sc2, bi2);
    bn_add_relu<<<ewGrid, 256, 0, stream>>>((float4*)outp, (const float4*)x, sc2, bi2);
}

// Round 6
// 945.819 us; speedup vs baseline: 6.2970x; 1.2737x over previous
//
#include <hip/hip_runtime.h>

// ShiftAddNet BasicBlock, N=64, C=planes=128, H=W=32, fp32.
// R6: adder via dual 16-bit SAD (v_sad_u16): activations+weights on a 1/2048
// grid, +32768 bias, two input channels packed per u32. Conv epilogue fuses
// quantize+pack (adder inner loop has zero conversion ops). Packed guard rows
// and DPP halo use biased-zero 0x80008000.

#define NB   64
#define CIN  128
#define HW   32
#define COUT 128
constexpr int PLANE    = HW * HW;        // 1024
constexpr int NPAIR    = CIN / 2;        // 64 packed ci-pair planes
constexpr int CI_CHUNK = 4;              // pair-planes per stage step
constexpr int CO_CHUNK = 8;
constexpr int LPLANE   = 34 * 32;        // guard row + 32 rows + guard row (u32 units)
constexpr int LDS_TOT  = 2 * CI_CHUNK * LPLANE;   // 8704 elems = 34816 B
constexpr float FSCALE    = 32768.0f;    // round_fixed scale
constexpr float INV_SCALE = 1.0f / 32768.0f;
constexpr float QS     = 2048.0f;        // adder fixed-point scale
constexpr float QB     = 32768.5f;       // bias + 0.5 for round-to-nearest
constexpr float INV_QS = 1.0f / 2048.0f;
constexpr unsigned PZ  = 0x80008000u;    // packed biased zero

#define GLOBAL_AS __attribute__((address_space(1)))
#define LDS_AS    __attribute__((address_space(3)))

__device__ __forceinline__ void gload_lds16(const void* g, void* l) {
    __builtin_amdgcn_global_load_lds((const GLOBAL_AS void*)g, (LDS_AS void*)l,
                                     16, 0, 0);
}

// lane n <- lane n-1 (row_shr:1); boundary lanes get 0 (bound_ctrl)
__device__ __forceinline__ float dpp_prev(float x) {
    return __int_as_float(__builtin_amdgcn_update_dpp(
        0, __float_as_int(x), 0x111, 0xF, 0xF, true));
}
__device__ __forceinline__ float dpp_next(float x) {
    return __int_as_float(__builtin_amdgcn_update_dpp(
        0, __float_as_int(x), 0x101, 0xF, 0xF, true));
}
__device__ __forceinline__ unsigned dpp_prev_u(unsigned x) {
    return (unsigned)__builtin_amdgcn_update_dpp(0, (int)x, 0x111, 0xF, 0xF, true);
}
__device__ __forceinline__ unsigned dpp_next_u(unsigned x) {
    return (unsigned)__builtin_amdgcn_update_dpp(0, (int)x, 0x101, 0xF, 0xF, true);
}

// stage one 4KB plane into LDS center rows (async, 4 x 1KB issues)
__device__ __forceinline__ void stage_plane4(const void* src, void* dst, int lane) {
#pragma unroll
    for (int i = 0; i < 4; ++i)
        gload_lds16((const char*)src + i * 1024 + lane * 16,
                    (char*)dst + 128 + i * 1024);
}

__device__ __forceinline__ unsigned q16(float a) {
    float t = fmaf(a, QS, QB);
    t = fminf(fmaxf(t, 0.0f), 65535.0f);
    return (unsigned)t;
}

// ---------------------------------------------------------------- shift conv
// fp32 in (with round_fixed), packed-u16-pair out: [n][co/2][h][w] u32
__global__ __launch_bounds__(256, 2) void conv_shift(
    const float* __restrict__ in, const float* __restrict__ wgt,
    unsigned* __restrict__ out)
{
    __shared__ __align__(16) float sIn[LDS_TOT];

    const int tid  = threadIdx.x;
    const int lane = tid & 63;
    const int wid  = tid >> 6;
    const int bid  = (blockIdx.x & 7) * 128 + (blockIdx.x >> 3);  // T1 swizzle
    const int n    = bid >> 4;
    const int co0  = (bid & 15) * CO_CHUNK;
    const int r    = tid >> 3;
    const int c    = tid & 7;
    const int c0   = c * 4;
    const bool cz  = (c == 0), c7 = (c == 7);

    float acc[4][CO_CHUNK];
#pragma unroll
    for (int p = 0; p < 4; ++p)
#pragma unroll
        for (int co = 0; co < CO_CHUNK; ++co) acc[p][co] = 0.0f;

    const float* inN = in + (size_t)n * CIN * PLANE;

    for (int idx = tid; idx < 512; idx += 256) {
        int slot = idx >> 6, wq = idx & 63;
        sIn[slot * LPLANE + (wq < 32 ? wq : 1024 + wq)] = 0.0f;
    }
    stage_plane4(inN + wid * PLANE, sIn + wid * LPLANE, lane);
    __syncthreads();

    int cur = 0;
    for (int ci0 = 0; ci0 < CIN; ci0 += CI_CHUNK) {
        if (ci0 + CI_CHUNK < CIN)
            stage_plane4(inN + (size_t)(ci0 + CI_CHUNK + wid) * PLANE,
                         sIn + ((cur ^ 1) * CI_CHUNK + wid) * LPLANE, lane);

        const float* sb = sIn + cur * CI_CHUNK * LPLANE;
#pragma unroll
        for (int cc = 0; cc < CI_CHUNK; ++cc) {
            float w[3][6];
#pragma unroll
            for (int dh = 0; dh < 3; ++dh) {
                const float* sp = sb + cc * LPLANE + (r + dh) * 32 + c0;
                float4 q = *reinterpret_cast<const float4*>(sp);
                q.x = rintf(q.x * FSCALE) * INV_SCALE;
                q.y = rintf(q.y * FSCALE) * INV_SCALE;
                q.z = rintf(q.z * FSCALE) * INV_SCALE;
                q.w = rintf(q.w * FSCALE) * INV_SCALE;
                float lf = dpp_prev(q.w);
                float rt = dpp_next(q.x);
                w[dh][0] = cz ? 0.0f : lf;
                w[dh][1] = q.x; w[dh][2] = q.y; w[dh][3] = q.z; w[dh][4] = q.w;
                w[dh][5] = c7 ? 0.0f : rt;
            }

            const float* wp = wgt + ((size_t)co0 * CIN + (ci0 + cc)) * 9;
#pragma unroll
            for (int co = 0; co < CO_CHUNK; ++co)
#pragma unroll
                for (int dh = 0; dh < 3; ++dh)
#pragma unroll
                    for (int dw = 0; dw < 3; ++dw) {
                        const float wvv = wp[(size_t)co * CIN * 9 + dh * 3 + dw];
#pragma unroll
                        for (int p = 0; p < 4; ++p)
                            acc[p][co] = fmaf(w[dh][p + dw], wvv, acc[p][co]);
                    }
        }
        __syncthreads();
        cur ^= 1;
    }

    // epilogue: quantize+pack co pairs -> [n][cp][h][w]
    unsigned* outP = out + ((size_t)n * NPAIR + co0 / 2) * PLANE + r * HW + c0;
#pragma unroll
    for (int pr = 0; pr < CO_CHUNK / 2; ++pr) {
        uint4 v;
        unsigned* vp = &v.x;
#pragma unroll
        for (int p = 0; p < 4; ++p) {
            unsigned lo = q16(acc[p][2 * pr]);
            unsigned hi = q16(acc[p][2 * pr + 1]);
            vp[p] = lo | (hi << 16);
        }
        *reinterpret_cast<uint4*>(&outP[pr * PLANE]) = v;
    }
}

// ---------------------------------------------------------------- adder conv
// packed-u16-pair in, fp32 out + fp64 BN stats. 1 v_sad_u16 per 2 terms.
__global__ __launch_bounds__(256, 2) void adder_packed(
    const unsigned* __restrict__ in, const unsigned* __restrict__ wq,
    float* __restrict__ out, double* __restrict__ ssum, double* __restrict__ ssq)
{
    __shared__ __align__(16) unsigned sIn[LDS_TOT];

    const int tid  = threadIdx.x;
    const int lane = tid & 63;
    const int wid  = tid >> 6;
    const int bid  = (blockIdx.x & 7) * 128 + (blockIdx.x >> 3);
    const int n    = bid >> 4;
    const int co0  = (bid & 15) * CO_CHUNK;
    const int r    = tid >> 3;
    const int c    = tid & 7;
    const int c0   = c * 4;
    const bool cz  = (c == 0), c7 = (c == 7);
    const unsigned pz = PZ;

    unsigned acc[4][CO_CHUNK];
#pragma unroll
    for (int p = 0; p < 4; ++p)
#pragma unroll
        for (int co = 0; co < CO_CHUNK; ++co) acc[p][co] = 0u;

    const unsigned* inN = in + (size_t)n * NPAIR * PLANE;

    // guard rows = packed biased zero
    for (int idx = tid; idx < 512; idx += 256) {
        int slot = idx >> 6, wqi = idx & 63;
        sIn[slot * LPLANE + (wqi < 32 ? wqi : 1024 + wqi)] = PZ;
    }
    stage_plane4(inN + wid * PLANE, sIn + wid * LPLANE, lane);
    __syncthreads();

    int cur = 0;
    for (int s = 0; s < NPAIR / CI_CHUNK; ++s) {           // 16 steps
        if (s + 1 < NPAIR / CI_CHUNK)
            stage_plane4(inN + (size_t)((s + 1) * CI_CHUNK + wid) * PLANE,
                         sIn + ((cur ^ 1) * CI_CHUNK + wid) * LPLANE, lane);

        const unsigned* sb = sIn + cur * CI_CHUNK * LPLANE;
#pragma unroll
        for (int cc = 0; cc < CI_CHUNK; ++cc) {
            unsigned wi[3][6];
#pragma unroll
            for (int dh = 0; dh < 3; ++dh) {
                const unsigned* sp = sb + cc * LPLANE + (r + dh) * 32 + c0;
                uint4 q = *reinterpret_cast<const uint4*>(sp);
                unsigned lf = dpp_prev_u(q.w);
                unsigned rt = dpp_next_u(q.x);
                wi[dh][0] = cz ? pz : lf;
                wi[dh][1] = q.x; wi[dh][2] = q.y; wi[dh][3] = q.z; wi[dh][4] = q.w;
                wi[dh][5] = c7 ? pz : rt;
            }

            const int cp = s * CI_CHUNK + cc;              // pair index 0..63
            const unsigned* wrow = wq + ((size_t)co0 * NPAIR + cp) * 9;
#pragma unroll
            for (int co = 0; co < CO_CHUNK; ++co)
#pragma unroll
                for (int dh = 0; dh < 3; ++dh)
#pragma unroll
                    for (int dw = 0; dw < 3; ++dw) {
                        const unsigned wv =
                            wrow[(size_t)co * NPAIR * 9 + dh * 3 + dw];
#pragma unroll
                        for (int p = 0; p < 4; ++p)
                            asm("v_sad_u16 %0, %1, %2, %0"
                                : "+v"(acc[p][co])
                                : "v"(wi[dh][p + dw]), "s"(wv));
                    }
        }
        __syncthreads();
        cur ^= 1;
    }

    float* outP = out + ((size_t)n * COUT + co0) * PLANE + r * HW + c0;
#pragma unroll
    for (int co = 0; co < CO_CHUNK; ++co) {
        float y0 = -(float)acc[0][co] * INV_QS;
        float y1 = -(float)acc[1][co] * INV_QS;
        float y2 = -(float)acc[2][co] * INV_QS;
        float y3 = -(float)acc[3][co] * INV_QS;
        *reinterpret_cast<float4*>(&outP[co * PLANE]) = make_float4(y0, y1, y2, y3);
        float s = (y0 + y1) + (y2 + y3);
        float q = fmaf(y0, y0, y1 * y1) + fmaf(y2, y2, y3 * y3);
#pragma unroll
        for (int m = 32; m > 0; m >>= 1) {
            s += __shfl_xor(s, m, 64);
            q += __shfl_xor(q, m, 64);
        }
        if (lane == 0) {
            atomicAdd(&ssum[co0 + co], (double)s);
            atomicAdd(&ssq [co0 + co], (double)q);
        }
    }
}

// ---------------------------------------------------------------- prep/BN
// pack adder weights: wq[layer][co][cp][tap] u32, 2 layers x 128 x 64 x 9
__global__ __launch_bounds__(256) void quant_pack_weights(
    const float* __restrict__ w1, const float* __restrict__ w2,
    unsigned* __restrict__ wq)
{
    int i = blockIdx.x * 256 + threadIdx.x;          // < 147456
    int layer = i >= 73728;
    int j   = i - layer * 73728;
    int co  = j / 576;
    int rem = j - co * 576;
    int cp  = rem / 9;
    int tap = rem - cp * 9;
    const float* w = layer ? w2 : w1;
    float f0 = w[((size_t)co * CIN + 2 * cp) * 9 + tap];
    float f1 = w[((size_t)co * CIN + 2 * cp + 1) * 9 + tap];
    wq[i] = q16(f0) | (q16(f1) << 16);
}

__global__ void zero_stats(double* st) {
    int i = threadIdx.x;
    st[i] = 0.0; st[i + 256] = 0.0;
}

__global__ void finalize_bn(const double* __restrict__ ssum, const double* __restrict__ ssq,
                            const float* __restrict__ gamma, const float* __restrict__ beta,
                            float* __restrict__ scale, float* __restrict__ bias)
{
    int c = threadIdx.x;  // 128
    const double cnt = (double)NB * PLANE;
    double m   = ssum[c] / cnt;
    double var = ssq[c] / cnt - m * m;
    double rstd = 1.0 / sqrt(var + 1e-5);
    float sc = (float)((double)gamma[c] * rstd);
    scale[c] = sc;
    bias[c]  = beta[c] - (float)m * sc;
}

__global__ __launch_bounds__(256) void bn_relu(
    float4* __restrict__ io, const float* __restrict__ scale,
    const float* __restrict__ bias)
{
    int i = blockIdx.x * 256 + threadIdx.x;
    int c = (i >> 8) & 127;
    float sc = scale[c], bs = bias[c];
    float4 v = io[i];
    v.x = fmaxf(fmaf(v.x, sc, bs), 0.0f);
    v.y = fmaxf(fmaf(v.y, sc, bs), 0.0f);
    v.z = fmaxf(fmaf(v.z, sc, bs), 0.0f);
    v.w = fmaxf(fmaf(v.w, sc, bs), 0.0f);
    io[i] = v;
}

__global__ __launch_bounds__(256) void bn_add_relu(
    float4* __restrict__ io, const float4* __restrict__ res,
    const float* __restrict__ scale, const float* __restrict__ bias)
{
    int i = blockIdx.x * 256 + threadIdx.x;
    int c = (i >> 8) & 127;
    float sc = scale[c], bs = bias[c];
    float4 v = io[i];
    float4 x = res[i];
    v.x = fmaxf(fmaf(v.x, sc, bs) + x.x, 0.0f);
    v.y = fmaxf(fmaf(v.y, sc, bs) + x.y, 0.0f);
    v.z = fmaxf(fmaf(v.z, sc, bs) + x.z, 0.0f);
    v.w = fmaxf(fmaf(v.w, sc, bs) + x.w, 0.0f);
    io[i] = v;
}

// ---------------------------------------------------------------- launch
extern "C" void kernel_launch(void* const* d_in, const int* in_sizes, int n_in,
                              void* d_out, int out_size, void* d_ws, size_t ws_size,
                              hipStream_t stream)
{
    const float* x    = (const float*)d_in[0];
    const float* wS1  = (const float*)d_in[1];
    const float* wA1  = (const float*)d_in[2];
    const float* g1   = (const float*)d_in[3];
    const float* b1   = (const float*)d_in[4];
    const float* wS2  = (const float*)d_in[5];
    const float* wA2  = (const float*)d_in[6];
    const float* g2   = (const float*)d_in[7];
    const float* b2   = (const float*)d_in[8];
    float* outp = (float*)d_out;

    char* ws = (char*)d_ws;
    unsigned* P  = (unsigned*)ws;                               // 16.78 MB packed
    double*   st = (double*)(ws + (size_t)NB * NPAIR * PLANE * 4);   // 512 doubles
    float*    sb = (float*)(st + 512);                          // 512 floats
    unsigned* wq = (unsigned*)(sb + 512);                       // 147456 u32

    double* s1 = st,       *q1 = st + 128;
    double* s2 = st + 256, *q2 = st + 384;
    float* sc1 = sb,       *bi1 = sb + 128;
    float* sc2 = sb + 256, *bi2 = sb + 384;

    const int convGrid = NB * (COUT / CO_CHUNK);          // 1024
    const int ewGrid   = (NB * COUT * PLANE / 4) / 256;   // 8192

    zero_stats<<<1, 256, 0, stream>>>(st);
    quant_pack_weights<<<147456 / 256, 256, 0, stream>>>(wA1, wA2, wq);

    // conv1: x -> packed P ; adder1: P -> d_out (fp32) + stats1
    conv_shift<<<convGrid, 256, 0, stream>>>(x, wS1, P);
    adder_packed<<<convGrid, 256, 0, stream>>>(P, wq, outp, s1, q1);
    finalize_bn<<<1, 128, 0, stream>>>(s1, q1, g1, b1, sc1, bi1);
    bn_relu<<<ewGrid, 256, 0, stream>>>((float4*)outp, sc1, bi1);      // in place
    // conv2: d_out -> packed P (reuse) ; adder2: P -> d_out + stats2
    conv_shift<<<convGrid, 256, 0, stream>>>(outp, wS2, P);
    adder_packed<<<convGrid, 256, 0, stream>>>(P, wq + 73728, outp, s2, q2);
    finalize_bn<<<1, 128, 0, stream>>>(s2, q2, g2, b2, sc2, bi2);
    bn_add_relu<<<ewGrid, 256, 0, stream>>>((float4*)outp, (const float4*)x, sc2, bi2);
}

// Round 7
// 525.307 us; speedup vs baseline: 11.3377x; 1.8005x over previous
//
#include <hip/hip_runtime.h>

// ShiftAddNet BasicBlock, N=64, C=planes=128, H=W=32, fp32.
// R7: shift convs on MFMA (f32_16x16x32_f16) with exact hi/lo fp16 activation
// split (weights are powers of two = exact in fp16). Transform kernels emit
// acts as fp16 pairs in a guard-rowed, XOR-swizzled global layout so conv
// staging is linear global_load_lds and ds_read_b128 is bank-conflict-free.
// Adder stays R6's v_sad_u16 path (unchanged). Fallback to R6 conv if ws small.

#define NB   64
#define CIN  128
#define HW   32
#define COUT 128
constexpr int PLANE    = HW * HW;        // 1024
constexpr int NPAIR    = CIN / 2;        // 64 packed ci-pair planes (adder)
constexpr int CI_CHUNK = 4;
constexpr int CO_CHUNK = 8;
constexpr int LPLANE   = 34 * 32;
constexpr int LDS_TOT  = 2 * CI_CHUNK * LPLANE;   // 34816 B (adder/fallback)
constexpr float FSCALE    = 32768.0f;
constexpr float INV_SCALE = 1.0f / 32768.0f;
constexpr float QS     = 2048.0f;
constexpr float QB     = 32768.5f;
constexpr float INV_QS = 1.0f / 2048.0f;
constexpr unsigned PZ  = 0x80008000u;

// G (split-act) layout: [n][ciq(4)][gr(34)][w(32)][sg(8)][e(8 f16)]
// gr = h+1 (0,33 = zero guards); sg = kgrp ^ (w&7); k = 2*ci_local+part
constexpr int G_ROWB   = 32 * 8 * 16;            // 4096 B per row
constexpr int G_CIQB   = 34 * G_ROWB;            // 139264 B
constexpr int G_NB     = 4 * G_CIQB;             // 557056 B per image

typedef _Float16 f16x8 __attribute__((ext_vector_type(8)));
typedef float    f32x4 __attribute__((ext_vector_type(4)));

#define GLOBAL_AS __attribute__((address_space(1)))
#define LDS_AS    __attribute__((address_space(3)))

__device__ __forceinline__ void gload_lds16(const void* g, void* l) {
    __builtin_amdgcn_global_load_lds((const GLOBAL_AS void*)g, (LDS_AS void*)l,
                                     16, 0, 0);
}
__device__ __forceinline__ float dpp_prev(float x) {
    return __int_as_float(__builtin_amdgcn_update_dpp(
        0, __float_as_int(x), 0x111, 0xF, 0xF, true));
}
__device__ __forceinline__ float dpp_next(float x) {
    return __int_as_float(__builtin_amdgcn_update_dpp(
        0, __float_as_int(x), 0x101, 0xF, 0xF, true));
}
__device__ __forceinline__ unsigned dpp_prev_u(unsigned x) {
    return (unsigned)__builtin_amdgcn_update_dpp(0, (int)x, 0x111, 0xF, 0xF, true);
}
__device__ __forceinline__ unsigned dpp_next_u(unsigned x) {
    return (unsigned)__builtin_amdgcn_update_dpp(0, (int)x, 0x101, 0xF, 0xF, true);
}
__device__ __forceinline__ void stage_plane4(const void* src, void* dst, int lane) {
#pragma unroll
    for (int i = 0; i < 4; ++i)
        gload_lds16((const char*)src + i * 1024 + lane * 16,
                    (char*)dst + 128 + i * 1024);
}
__device__ __forceinline__ unsigned q16(float a) {
    float t = fmaf(a, QS, QB);
    t = fminf(fmaxf(t, 0.0f), 65535.0f);
    return (unsigned)t;
}
__device__ __forceinline__ unsigned packhl(float v) {
    _Float16 h = (_Float16)v;
    _Float16 l = (_Float16)(v - (float)h);          // exact residual
    unsigned uh = (unsigned)__builtin_bit_cast(unsigned short, h);
    unsigned ul = (unsigned)__builtin_bit_cast(unsigned short, l);
    return uh | (ul << 16);
}

// ============================================================ MFMA conv path
// transform: fp32 NCHW (+optional BN+ReLU) -> round_fixed -> hi/lo fp16 -> G
template <int WITH_BN>
__global__ __launch_bounds__(256) void transform_split(
    const float* __restrict__ in, const float* __restrict__ scale,
    const float* __restrict__ bias, uint4* __restrict__ G)
{
    __shared__ float sT[32 * 132];
    const int tid = threadIdx.x;
    const int b   = blockIdx.x;            // 2048 = 64n * 4ciq * 8rq
    const int n   = b >> 5;
    const int ciq = (b >> 3) & 3;
    const int rq  = b & 7;

    // phase 1: coalesced load of 32 ci x 128 px (4 rows), BN+ReLU+round
#pragma unroll
    for (int it = 0; it < 4; ++it) {
        int flat = it * 256 + tid;
        int ci_rel = flat >> 5;
        int px4 = (flat & 31) * 4;
        const float* ap = in + ((size_t)(n * CIN + ciq * 32 + ci_rel)) * PLANE
                             + rq * 128 + px4;
        float4 v = *reinterpret_cast<const float4*>(ap);
        if (WITH_BN) {
            float sc = scale[ciq * 32 + ci_rel], bs = bias[ciq * 32 + ci_rel];
            v.x = fmaxf(fmaf(v.x, sc, bs), 0.0f);
            v.y = fmaxf(fmaf(v.y, sc, bs), 0.0f);
            v.z = fmaxf(fmaf(v.z, sc, bs), 0.0f);
            v.w = fmaxf(fmaf(v.w, sc, bs), 0.0f);
        }
        v.x = rintf(v.x * FSCALE) * INV_SCALE;
        v.y = rintf(v.y * FSCALE) * INV_SCALE;
        v.z = rintf(v.z * FSCALE) * INV_SCALE;
        v.w = rintf(v.w * FSCALE) * INV_SCALE;
        *reinterpret_cast<float4*>(&sT[ci_rel * 132 + px4]) = v;
    }
    __syncthreads();

    uint4* Gp = G + ((size_t)n * G_NB + ciq * G_CIQB) / 16;
    // phase 2: swizzled fp16-pair units, coalesced 16B writes
#pragma unroll
    for (int it = 0; it < 4; ++it) {
        int f = it * 256 + tid;            // 1024 units (4 rows x 32 w x 8 sg)
        int row_loc = f >> 8;
        int rem = f & 255;
        int w  = rem >> 3;
        int sg = rem & 7;
        int g  = sg ^ (w & 7);
        uint4 u;
        unsigned* up = &u.x;
#pragma unroll
        for (int j = 0; j < 4; ++j)
            up[j] = packhl(sT[(g * 4 + j) * 132 + row_loc * 32 + w]);
        int gr = rq * 4 + row_loc + 1;
        Gp[(gr * 32 + w) * 8 + sg] = u;
    }
    // guard rows (gr 0 and 33) = zeros
    if (rq == 0) Gp[tid] = make_uint4(0, 0, 0, 0);
    if (rq == 7) Gp[33 * 256 + tid] = make_uint4(0, 0, 0, 0);
}

// weight prep: WF[tap][ciq][kch][cot][lane][4 dwords], each dword = dup f16
__global__ __launch_bounds__(256) void wf_prep(
    const float* __restrict__ w1, const float* __restrict__ w2,
    unsigned* __restrict__ WF)
{
    int i = blockIdx.x * 256 + threadIdx.x;   // < 294912 (2 layers x 147456)
    int layer = i >= 147456;
    int idx = i - layer * 147456;
    int j2  = idx & 3;
    int l   = (idx >> 2) & 63;
    int cot = (idx >> 8) & 7;
    int kch = (idx >> 11) & 1;
    int ciq = (idx >> 12) & 3;
    int tap = idx >> 14;                      // 0..8
    int ci  = ciq * 32 + kch * 16 + (l >> 4) * 4 + j2;
    int co  = cot * 16 + (l & 15);
    const float* w = layer ? w2 : w1;
    float v = w[((size_t)co * CIN + ci) * 9 + tap];
    unsigned h = (unsigned)__builtin_bit_cast(unsigned short, (_Float16)v);
    WF[i] = h | (h << 16);
}

// conv via MFMA: G (split acts) x WF -> P (packed u16 co-pairs)
__global__ __launch_bounds__(256, 1) void conv_mfma(
    const uint4* __restrict__ G, const uint4* __restrict__ WF,
    unsigned* __restrict__ P)
{
    __shared__ uint4 sA[2560];                // 40960 B: 10 rows x 4096
    const int tid  = threadIdx.x;
    const int lane = tid & 63;
    const int wid  = tid >> 6;
    const int b    = (blockIdx.x & 7) * 32 + (blockIdx.x >> 3);  // XCD swizzle
    const int n    = b >> 2;
    const int q    = b & 3;                   // 8-row quarter
    const int glo16 = (lane >> 4) * 16;

    f32x4 acc[8][4];
#pragma unroll
    for (int i = 0; i < 8; ++i)
#pragma unroll
        for (int j = 0; j < 4; ++j) acc[i][j] = (f32x4){0.f, 0.f, 0.f, 0.f};

    for (int ciq = 0; ciq < 4; ++ciq) {
        if (ciq) __syncthreads();
        const char* src = (const char*)G + (size_t)n * G_NB + ciq * G_CIQB
                        + q * 8 * G_ROWB;
#pragma unroll
        for (int i = 0; i < 10; ++i) {
            int off = (i * 4 + wid) * 1024;
            gload_lds16(src + off + lane * 16, (char*)sA + off);
        }
        __syncthreads();

        for (int dh = 0; dh < 3; ++dh)
            for (int dw = 0; dw < 3; ++dw) {
                const int tap = dh * 3 + dw;
#pragma unroll
                for (int kch = 0; kch < 2; ++kch) {
                    const uint4* wfp = WF + ((size_t)((tap * 4 + ciq) * 2 + kch)) * 512 + lane;
                    f16x8 a[8];
#pragma unroll
                    for (int cot = 0; cot < 8; ++cot)
                        a[cot] = __builtin_bit_cast(f16x8, wfp[cot * 64]);
#pragma unroll
                    for (int p = 0; p < 4; ++p) {
                        int pw = (p & 1) * 16 + (lane & 15);
                        int wpr = pw + dw - 1;
                        bool ok = (unsigned)wpr < 32u;
                        int wq2 = ok ? wpr : 0;
                        int addr = (wid * 2 + (p >> 1) + dh) * 4096 + wq2 * 128
                                 + (((kch * 64) | glo16) ^ ((wq2 & 7) * 16));
                        uint4 braw = *reinterpret_cast<const uint4*>(
                            (const char*)sA + addr);
                        if (dw != 1) {
                            braw.x = ok ? braw.x : 0u;
                            braw.y = ok ? braw.y : 0u;
                            braw.z = ok ? braw.z : 0u;
                            braw.w = ok ? braw.w : 0u;
                        }
                        f16x8 bf = __builtin_bit_cast(f16x8, braw);
#pragma unroll
                        for (int cot = 0; cot < 8; ++cot)
                            acc[cot][p] = __builtin_amdgcn_mfma_f32_16x16x32_f16(
                                a[cot], bf, acc[cot][p], 0, 0, 0);
                    }
                }
            }
    }

    // epilogue: quantize + pack co-pairs into P [n][cp][px]
    unsigned* Pn = P + (size_t)n * NPAIR * PLANE;
    const int r0 = q * 8 + wid * 2;
#pragma unroll
    for (int cot = 0; cot < 8; ++cot) {
        int cp = cot * 8 + (lane >> 4) * 2;
#pragma unroll
        for (int p = 0; p < 4; ++p) {
            int px = (r0 + (p >> 1)) * 32 + (p & 1) * 16 + (lane & 15);
            unsigned u01 = q16(acc[cot][p][0]) | (q16(acc[cot][p][1]) << 16);
            unsigned u23 = q16(acc[cot][p][2]) | (q16(acc[cot][p][3]) << 16);
            Pn[cp * PLANE + px] = u01;
            Pn[(cp + 1) * PLANE + px] = u23;
        }
    }
}

// ============================================================ fallback conv
__global__ __launch_bounds__(256, 2) void conv_shift_valu(
    const float* __restrict__ in, const float* __restrict__ wgt,
    unsigned* __restrict__ out)
{
    __shared__ __align__(16) float sIn[LDS_TOT];
    const int tid  = threadIdx.x;
    const int lane = tid & 63;
    const int wid  = tid >> 6;
    const int bid  = (blockIdx.x & 7) * 128 + (blockIdx.x >> 3);
    const int n    = bid >> 4;
    const int co0  = (bid & 15) * CO_CHUNK;
    const int r    = tid >> 3;
    const int c    = tid & 7;
    const int c0   = c * 4;
    const bool cz  = (c == 0), c7 = (c == 7);

    float acc[4][CO_CHUNK];
#pragma unroll
    for (int p = 0; p < 4; ++p)
#pragma unroll
        for (int co = 0; co < CO_CHUNK; ++co) acc[p][co] = 0.0f;

    const float* inN = in + (size_t)n * CIN * PLANE;
    for (int idx = tid; idx < 512; idx += 256) {
        int slot = idx >> 6, wq = idx & 63;
        sIn[slot * LPLANE + (wq < 32 ? wq : 1024 + wq)] = 0.0f;
    }
    stage_plane4(inN + wid * PLANE, sIn + wid * LPLANE, lane);
    __syncthreads();

    int cur = 0;
    for (int ci0 = 0; ci0 < CIN; ci0 += CI_CHUNK) {
        if (ci0 + CI_CHUNK < CIN)
            stage_plane4(inN + (size_t)(ci0 + CI_CHUNK + wid) * PLANE,
                         sIn + ((cur ^ 1) * CI_CHUNK + wid) * LPLANE, lane);
        const float* sb = sIn + cur * CI_CHUNK * LPLANE;
#pragma unroll
        for (int cc = 0; cc < CI_CHUNK; ++cc) {
            float w[3][6];
#pragma unroll
            for (int dh = 0; dh < 3; ++dh) {
                const float* sp = sb + cc * LPLANE + (r + dh) * 32 + c0;
                float4 qv = *reinterpret_cast<const float4*>(sp);
                qv.x = rintf(qv.x * FSCALE) * INV_SCALE;
                qv.y = rintf(qv.y * FSCALE) * INV_SCALE;
                qv.z = rintf(qv.z * FSCALE) * INV_SCALE;
                qv.w = rintf(qv.w * FSCALE) * INV_SCALE;
                float lf = dpp_prev(qv.w);
                float rt = dpp_next(qv.x);
                w[dh][0] = cz ? 0.0f : lf;
                w[dh][1] = qv.x; w[dh][2] = qv.y; w[dh][3] = qv.z; w[dh][4] = qv.w;
                w[dh][5] = c7 ? 0.0f : rt;
            }
            const float* wp = wgt + ((size_t)co0 * CIN + (ci0 + cc)) * 9;
#pragma unroll
            for (int co = 0; co < CO_CHUNK; ++co)
#pragma unroll
                for (int dh = 0; dh < 3; ++dh)
#pragma unroll
                    for (int dw = 0; dw < 3; ++dw) {
                        const float wvv = wp[(size_t)co * CIN * 9 + dh * 3 + dw];
#pragma unroll
                        for (int p = 0; p < 4; ++p)
                            acc[p][co] = fmaf(w[dh][p + dw], wvv, acc[p][co]);
                    }
        }
        __syncthreads();
        cur ^= 1;
    }
    unsigned* outP = out + ((size_t)n * NPAIR + co0 / 2) * PLANE + r * HW + c0;
#pragma unroll
    for (int pr = 0; pr < CO_CHUNK / 2; ++pr) {
        uint4 v;
        unsigned* vp = &v.x;
#pragma unroll
        for (int p = 0; p < 4; ++p)
            vp[p] = q16(acc[p][2 * pr]) | (q16(acc[p][2 * pr + 1]) << 16);
        *reinterpret_cast<uint4*>(&outP[pr * PLANE]) = v;
    }
}

__global__ __launch_bounds__(256) void bn_relu_inplace(
    float4* __restrict__ io, const float* __restrict__ scale,
    const float* __restrict__ bias)
{
    int i = blockIdx.x * 256 + threadIdx.x;
    int c = (i >> 8) & 127;
    float sc = scale[c], bs = bias[c];
    float4 v = io[i];
    v.x = fmaxf(fmaf(v.x, sc, bs), 0.0f);
    v.y = fmaxf(fmaf(v.y, sc, bs), 0.0f);
    v.z = fmaxf(fmaf(v.z, sc, bs), 0.0f);
    v.w = fmaxf(fmaf(v.w, sc, bs), 0.0f);
    io[i] = v;
}

// ============================================================ adder (R6)
__global__ __launch_bounds__(256, 2) void adder_packed(
    const unsigned* __restrict__ in, const unsigned* __restrict__ wq,
    float* __restrict__ out, double* __restrict__ ssum, double* __restrict__ ssq)
{
    __shared__ __align__(16) unsigned sIn[LDS_TOT];
    const int tid  = threadIdx.x;
    const int lane = tid & 63;
    const int wid  = tid >> 6;
    const int bid  = (blockIdx.x & 7) * 128 + (blockIdx.x >> 3);
    const int n    = bid >> 4;
    const int co0  = (bid & 15) * CO_CHUNK;
    const int r    = tid >> 3;
    const int c    = tid & 7;
    const int c0   = c * 4;
    const bool cz  = (c == 0), c7 = (c == 7);
    const unsigned pz = PZ;

    unsigned acc[4][CO_CHUNK];
#pragma unroll
    for (int p = 0; p < 4; ++p)
#pragma unroll
        for (int co = 0; co < CO_CHUNK; ++co) acc[p][co] = 0u;

    const unsigned* inN = in + (size_t)n * NPAIR * PLANE;
    for (int idx = tid; idx < 512; idx += 256) {
        int slot = idx >> 6, wqi = idx & 63;
        sIn[slot * LPLANE + (wqi < 32 ? wqi : 1024 + wqi)] = PZ;
    }
    stage_plane4(inN + wid * PLANE, sIn + wid * LPLANE, lane);
    __syncthreads();

    int cur = 0;
    for (int s = 0; s < NPAIR / CI_CHUNK; ++s) {
        if (s + 1 < NPAIR / CI_CHUNK)
            stage_plane4(inN + (size_t)((s + 1) * CI_CHUNK + wid) * PLANE,
                         sIn + ((cur ^ 1) * CI_CHUNK + wid) * LPLANE, lane);
        const unsigned* sb = sIn + cur * CI_CHUNK * LPLANE;
#pragma unroll
        for (int cc = 0; cc < CI_CHUNK; ++cc) {
            unsigned wi[3][6];
#pragma unroll
            for (int dh = 0; dh < 3; ++dh) {
                const unsigned* sp = sb + cc * LPLANE + (r + dh) * 32 + c0;
                uint4 qv = *reinterpret_cast<const uint4*>(sp);
                unsigned lf = dpp_prev_u(qv.w);
                unsigned rt = dpp_next_u(qv.x);
                wi[dh][0] = cz ? pz : lf;
                wi[dh][1] = qv.x; wi[dh][2] = qv.y; wi[dh][3] = qv.z; wi[dh][4] = qv.w;
                wi[dh][5] = c7 ? pz : rt;
            }
            const int cp = s * CI_CHUNK + cc;
            const unsigned* wrow = wq + ((size_t)co0 * NPAIR + cp) * 9;
#pragma unroll
            for (int co = 0; co < CO_CHUNK; ++co)
#pragma unroll
                for (int dh = 0; dh < 3; ++dh)
#pragma unroll
                    for (int dw = 0; dw < 3; ++dw) {
                        const unsigned wv =
                            wrow[(size_t)co * NPAIR * 9 + dh * 3 + dw];
#pragma unroll
                        for (int p = 0; p < 4; ++p)
                            asm("v_sad_u16 %0, %1, %2, %0"
                                : "+v"(acc[p][co])
                                : "v"(wi[dh][p + dw]), "s"(wv));
                    }
        }
        __syncthreads();
        cur ^= 1;
    }

    float* outP = out + ((size_t)n * COUT + co0) * PLANE + r * HW + c0;
#pragma unroll
    for (int co = 0; co < CO_CHUNK; ++co) {
        float y0 = -(float)acc[0][co] * INV_QS;
        float y1 = -(float)acc[1][co] * INV_QS;
        float y2 = -(float)acc[2][co] * INV_QS;
        float y3 = -(float)acc[3][co] * INV_QS;
        *reinterpret_cast<float4*>(&outP[co * PLANE]) = make_float4(y0, y1, y2, y3);
        float s = (y0 + y1) + (y2 + y3);
        float q = fmaf(y0, y0, y1 * y1) + fmaf(y2, y2, y3 * y3);
#pragma unroll
        for (int m = 32; m > 0; m >>= 1) {
            s += __shfl_xor(s, m, 64);
            q += __shfl_xor(q, m, 64);
        }
        if (lane == 0) {
            atomicAdd(&ssum[co0 + co], (double)s);
            atomicAdd(&ssq [co0 + co], (double)q);
        }
    }
}

// ============================================================ prep / BN
__global__ __launch_bounds__(256) void quant_pack_weights(
    const float* __restrict__ w1, const float* __restrict__ w2,
    unsigned* __restrict__ wq)
{
    int i = blockIdx.x * 256 + threadIdx.x;          // < 147456
    int layer = i >= 73728;
    int j   = i - layer * 73728;
    int co  = j / 576;
    int rem = j - co * 576;
    int cp  = rem / 9;
    int tap = rem - cp * 9;
    const float* w = layer ? w2 : w1;
    float f0 = w[((size_t)co * CIN + 2 * cp) * 9 + tap];
    float f1 = w[((size_t)co * CIN + 2 * cp + 1) * 9 + tap];
    wq[i] = q16(f0) | (q16(f1) << 16);
}

__global__ void zero_stats(double* st) {
    int i = threadIdx.x;
    st[i] = 0.0; st[i + 256] = 0.0;
}

__global__ void finalize_bn(const double* __restrict__ ssum, const double* __restrict__ ssq,
                            const float* __restrict__ gamma, const float* __restrict__ beta,
                            float* __restrict__ scale, float* __restrict__ bias)
{
    int c = threadIdx.x;  // 128
    const double cnt = (double)NB * PLANE;
    double m   = ssum[c] / cnt;
    double var = ssq[c] / cnt - m * m;
    double rstd = 1.0 / sqrt(var + 1e-5);
    float sc = (float)((double)gamma[c] * rstd);
    scale[c] = sc;
    bias[c]  = beta[c] - (float)m * sc;
}

__global__ __launch_bounds__(256) void bn_add_relu(
    float4* __restrict__ io, const float4* __restrict__ res,
    const float* __restrict__ scale, const float* __restrict__ bias)
{
    int i = blockIdx.x * 256 + threadIdx.x;
    int c = (i >> 8) & 127;
    float sc = scale[c], bs = bias[c];
    float4 v = io[i];
    float4 x = res[i];
    v.x = fmaxf(fmaf(v.x, sc, bs) + x.x, 0.0f);
    v.y = fmaxf(fmaf(v.y, sc, bs) + x.y, 0.0f);
    v.z = fmaxf(fmaf(v.z, sc, bs) + x.z, 0.0f);
    v.w = fmaxf(fmaf(v.w, sc, bs) + x.w, 0.0f);
    io[i] = v;
}

// ============================================================ launch
extern "C" void kernel_launch(void* const* d_in, const int* in_sizes, int n_in,
                              void* d_out, int out_size, void* d_ws, size_t ws_size,
                              hipStream_t stream)
{
    const float* x    = (const float*)d_in[0];
    const float* wS1  = (const float*)d_in[1];
    const float* wA1  = (const float*)d_in[2];
    const float* g1   = (const float*)d_in[3];
    const float* b1   = (const float*)d_in[4];
    const float* wS2  = (const float*)d_in[5];
    const float* wA2  = (const float*)d_in[6];
    const float* g2   = (const float*)d_in[7];
    const float* b2   = (const float*)d_in[8];
    float* outp = (float*)d_out;

    char* ws = (char*)d_ws;
    const size_t MFMA_WS = 54204416;
    const bool mf = ws_size >= MFMA_WS;

    unsigned* P = (unsigned*)ws;                    // 16,777,216 B
    double* st; float* sb; unsigned* wq; char* Gb = nullptr; unsigned* WF = nullptr;
    if (mf) {
        Gb = ws + 16777216;                         // 35,651,584 B
        st = (double*)(ws + 52428800);
        sb = (float*)(ws + 52432896);
        wq = (unsigned*)(ws + 52434944);            // 589,824 B
        WF = (unsigned*)(ws + 53024768);            // 1,179,648 B
    } else {
        st = (double*)(ws + 16777216);
        sb = (float*)(st + 512);
        wq = (unsigned*)(sb + 512);
    }
    double* s1 = st,       *q1 = st + 128;
    double* s2 = st + 256, *q2 = st + 384;
    float* sc1 = sb,       *bi1 = sb + 128;
    float* sc2 = sb + 256, *bi2 = sb + 384;

    const int convGrid = NB * (COUT / CO_CHUNK);          // 1024
    const int ewGrid   = (NB * COUT * PLANE / 4) / 256;   // 8192

    zero_stats<<<1, 256, 0, stream>>>(st);
    quant_pack_weights<<<576, 256, 0, stream>>>(wA1, wA2, wq);

    if (mf) {
        wf_prep<<<1152, 256, 0, stream>>>(wS1, wS2, WF);
        transform_split<0><<<2048, 256, 0, stream>>>(x, nullptr, nullptr, (uint4*)Gb);
        conv_mfma<<<256, 256, 0, stream>>>((const uint4*)Gb, (const uint4*)WF, P);
        adder_packed<<<convGrid, 256, 0, stream>>>(P, wq, outp, s1, q1);
        finalize_bn<<<1, 128, 0, stream>>>(s1, q1, g1, b1, sc1, bi1);
        transform_split<1><<<2048, 256, 0, stream>>>(outp, sc1, bi1, (uint4*)Gb);
        conv_mfma<<<256, 256, 0, stream>>>((const uint4*)Gb,
                                           (const uint4*)(WF + 147456), P);
        adder_packed<<<convGrid, 256, 0, stream>>>(P, wq + 73728, outp, s2, q2);
        finalize_bn<<<1, 128, 0, stream>>>(s2, q2, g2, b2, sc2, bi2);
        bn_add_relu<<<ewGrid, 256, 0, stream>>>((float4*)outp, (const float4*)x,
                                                sc2, bi2);
    } else {
        conv_shift_valu<<<convGrid, 256, 0, stream>>>(x, wS1, P);
        adder_packed<<<convGrid, 256, 0, stream>>>(P, wq, outp, s1, q1);
        finalize_bn<<<1, 128, 0, stream>>>(s1, q1, g1, b1, sc1, bi1);
        bn_relu_inplace<<<ewGrid, 256, 0, stream>>>((float4*)outp, sc1, bi1);
        conv_shift_valu<<<convGrid, 256, 0, stream>>>(outp, wS2, P);
        adder_packed<<<convGrid, 256, 0, stream>>>(P, wq + 73728, outp, s2, q2);
        finalize_bn<<<1, 128, 0, stream>>>(s2, q2, g2, b2, sc2, bi2);
        bn_add_relu<<<ewGrid, 256, 0, stream>>>((float4*)outp, (const float4*)x,
                                                sc2, bi2);
    }
}

// Round 8
// 465.077 us; speedup vs baseline: 12.8060x; 1.1295x over previous
//
#include <hip/hip_runtime.h>

// ShiftAddNet BasicBlock, N=64, C=planes=128, H=W=32, fp32.
// R8: (1) adder at 8 blocks/CU (CO=4, CI_CHUNK=2, lb(256,8)) for latency
// hiding; (2) conv_mfma 4-row blocks (grid 512, 2/CU) with register B-rows +
// DPP-derived dw=0/2 fragments (fewer LDS reads). Numerics unchanged.

#define NB   64
#define CIN  128
#define HW   32
#define COUT 128
constexpr int PLANE    = HW * HW;        // 1024
constexpr int NPAIR    = CIN / 2;        // 64 packed ci-pair planes (adder)
constexpr int CI_CHUNK = 4;              // fallback conv only
constexpr int CO_CHUNK = 8;              // fallback conv only
constexpr int LPLANE   = 34 * 32;
constexpr int LDS_TOT  = 2 * CI_CHUNK * LPLANE;   // fallback conv LDS
constexpr int A_CI     = 2;              // adder pair-planes per step
constexpr int A_CO     = 4;              // adder co per block
constexpr int A_LDS    = 2 * A_CI * LPLANE;       // 4352 u32 = 17408 B
constexpr float FSCALE    = 32768.0f;
constexpr float INV_SCALE = 1.0f / 32768.0f;
constexpr float QS     = 2048.0f;
constexpr float QB     = 32768.5f;
constexpr float INV_QS = 1.0f / 2048.0f;
constexpr unsigned PZ  = 0x80008000u;

// G (split-act) layout: [n][ciq(4)][gr(34)][w(32)][sg(8)][e(8 f16)]
constexpr int G_ROWB   = 32 * 8 * 16;            // 4096 B per row
constexpr int G_CIQB   = 34 * G_ROWB;            // 139264 B
constexpr int G_NB     = 4 * G_CIQB;             // 557056 B per image

typedef _Float16 f16x8 __attribute__((ext_vector_type(8)));
typedef float    f32x4 __attribute__((ext_vector_type(4)));

#define GLOBAL_AS __attribute__((address_space(1)))
#define LDS_AS    __attribute__((address_space(3)))

__device__ __forceinline__ void gload_lds16(const void* g, void* l) {
    __builtin_amdgcn_global_load_lds((const GLOBAL_AS void*)g, (LDS_AS void*)l,
                                     16, 0, 0);
}
__device__ __forceinline__ float dpp_prev(float x) {
    return __int_as_float(__builtin_amdgcn_update_dpp(
        0, __float_as_int(x), 0x111, 0xF, 0xF, true));
}
__device__ __forceinline__ float dpp_next(float x) {
    return __int_as_float(__builtin_amdgcn_update_dpp(
        0, __float_as_int(x), 0x101, 0xF, 0xF, true));
}
__device__ __forceinline__ unsigned dpp_prev_u(unsigned x) {
    return (unsigned)__builtin_amdgcn_update_dpp(0, (int)x, 0x111, 0xF, 0xF, true);
}
__device__ __forceinline__ unsigned dpp_next_u(unsigned x) {
    return (unsigned)__builtin_amdgcn_update_dpp(0, (int)x, 0x101, 0xF, 0xF, true);
}
__device__ __forceinline__ uint4 dpp4_shr(uint4 v) {   // lane l <- l-1 (px-1)
    uint4 r;
    r.x = dpp_prev_u(v.x); r.y = dpp_prev_u(v.y);
    r.z = dpp_prev_u(v.z); r.w = dpp_prev_u(v.w);
    return r;
}
__device__ __forceinline__ uint4 dpp4_shl(uint4 v) {   // lane l <- l+1 (px+1)
    uint4 r;
    r.x = dpp_next_u(v.x); r.y = dpp_next_u(v.y);
    r.z = dpp_next_u(v.z); r.w = dpp_next_u(v.w);
    return r;
}
__device__ __forceinline__ void stage_plane4(const void* src, void* dst, int lane) {
#pragma unroll
    for (int i = 0; i < 4; ++i)
        gload_lds16((const char*)src + i * 1024 + lane * 16,
                    (char*)dst + 128 + i * 1024);
}
__device__ __forceinline__ unsigned q16(float a) {
    float t = fmaf(a, QS, QB);
    t = fminf(fmaxf(t, 0.0f), 65535.0f);
    return (unsigned)t;
}
__device__ __forceinline__ unsigned packhl(float v) {
    _Float16 h = (_Float16)v;
    _Float16 l = (_Float16)(v - (float)h);          // exact residual
    unsigned uh = (unsigned)__builtin_bit_cast(unsigned short, h);
    unsigned ul = (unsigned)__builtin_bit_cast(unsigned short, l);
    return uh | (ul << 16);
}

// ============================================================ MFMA conv path
template <int WITH_BN>
__global__ __launch_bounds__(256) void transform_split(
    const float* __restrict__ in, const float* __restrict__ scale,
    const float* __restrict__ bias, uint4* __restrict__ G)
{
    __shared__ float sT[32 * 132];
    const int tid = threadIdx.x;
    const int b   = blockIdx.x;            // 2048 = 64n * 4ciq * 8rq
    const int n   = b >> 5;
    const int ciq = (b >> 3) & 3;
    const int rq  = b & 7;

#pragma unroll
    for (int it = 0; it < 4; ++it) {
        int flat = it * 256 + tid;
        int ci_rel = flat >> 5;
        int px4 = (flat & 31) * 4;
        const float* ap = in + ((size_t)(n * CIN + ciq * 32 + ci_rel)) * PLANE
                             + rq * 128 + px4;
        float4 v = *reinterpret_cast<const float4*>(ap);
        if (WITH_BN) {
            float sc = scale[ciq * 32 + ci_rel], bs = bias[ciq * 32 + ci_rel];
            v.x = fmaxf(fmaf(v.x, sc, bs), 0.0f);
            v.y = fmaxf(fmaf(v.y, sc, bs), 0.0f);
            v.z = fmaxf(fmaf(v.z, sc, bs), 0.0f);
            v.w = fmaxf(fmaf(v.w, sc, bs), 0.0f);
        }
        v.x = rintf(v.x * FSCALE) * INV_SCALE;
        v.y = rintf(v.y * FSCALE) * INV_SCALE;
        v.z = rintf(v.z * FSCALE) * INV_SCALE;
        v.w = rintf(v.w * FSCALE) * INV_SCALE;
        *reinterpret_cast<float4*>(&sT[ci_rel * 132 + px4]) = v;
    }
    __syncthreads();

    uint4* Gp = G + ((size_t)n * G_NB + ciq * G_CIQB) / 16;
#pragma unroll
    for (int it = 0; it < 4; ++it) {
        int f = it * 256 + tid;
        int row_loc = f >> 8;
        int rem = f & 255;
        int w  = rem >> 3;
        int sg = rem & 7;
        int g  = sg ^ (w & 7);
        uint4 u;
        unsigned* up = &u.x;
#pragma unroll
        for (int j = 0; j < 4; ++j)
            up[j] = packhl(sT[(g * 4 + j) * 132 + row_loc * 32 + w]);
        int gr = rq * 4 + row_loc + 1;
        Gp[(gr * 32 + w) * 8 + sg] = u;
    }
    if (rq == 0) Gp[tid] = make_uint4(0, 0, 0, 0);
    if (rq == 7) Gp[33 * 256 + tid] = make_uint4(0, 0, 0, 0);
}

// weight prep: WF[tap][ciq][kch][cot][lane][4 dwords], each dword = dup f16
__global__ __launch_bounds__(256) void wf_prep(
    const float* __restrict__ w1, const float* __restrict__ w2,
    unsigned* __restrict__ WF)
{
    int i = blockIdx.x * 256 + threadIdx.x;
    int layer = i >= 147456;
    int idx = i - layer * 147456;
    int j2  = idx & 3;
    int l   = (idx >> 2) & 63;
    int cot = (idx >> 8) & 7;
    int kch = (idx >> 11) & 1;
    int ciq = (idx >> 12) & 3;
    int tap = idx >> 14;
    int ci  = ciq * 32 + kch * 16 + (l >> 4) * 4 + j2;
    int co  = cot * 16 + (l & 15);
    const float* w = layer ? w2 : w1;
    float v = w[((size_t)co * CIN + ci) * 9 + tap];
    unsigned h = (unsigned)__builtin_bit_cast(unsigned short, (_Float16)v);
    WF[i] = h | (h << 16);
}

// conv via MFMA: 4-row blocks, register B-rows, DPP-derived dw fragments
__global__ __launch_bounds__(256, 2) void conv_mfma(
    const uint4* __restrict__ G, const uint4* __restrict__ WF,
    unsigned* __restrict__ P)
{
    __shared__ uint4 sA[1536];                // 24576 B: 6 rows x 4096
    const int tid  = threadIdx.x;
    const int lane = tid & 63;
    const int wid  = tid >> 6;
    const int b    = (blockIdx.x & 7) * 64 + (blockIdx.x >> 3);  // 512 blocks
    const int n    = b >> 3;
    const int q4   = b & 7;                   // 4-row slice
    const int glo16 = (lane >> 4) * 16;

    f32x4 acc[8][2];
#pragma unroll
    for (int i = 0; i < 8; ++i)
#pragma unroll
        for (int j = 0; j < 2; ++j) acc[i][j] = (f32x4){0.f, 0.f, 0.f, 0.f};

    for (int ciq = 0; ciq < 4; ++ciq) {
        if (ciq) __syncthreads();
        const char* src = (const char*)G + (size_t)n * G_NB + ciq * G_CIQB
                        + (size_t)q4 * 4 * G_ROWB;
#pragma unroll
        for (int i = 0; i < 6; ++i) {
            int off = i * 4096 + wid * 1024;
            gload_lds16(src + off + lane * 16, (char*)sA + off);
        }
        __syncthreads();

#pragma unroll
        for (int kch = 0; kch < 2; ++kch) {
            // both col-halves' 3 center row fragments -> regs
            uint4 Brow[2][3];
            int pwh[2];
#pragma unroll
            for (int half = 0; half < 2; ++half) {
                pwh[half] = half * 16 + (lane & 15);
                int cb = ((kch * 64) | glo16) ^ ((pwh[half] & 7) * 16);
#pragma unroll
                for (int rr = 0; rr < 3; ++rr)
                    Brow[half][rr] = *reinterpret_cast<const uint4*>(
                        (const char*)sA + (wid + rr) * 4096 + pwh[half] * 128 + cb);
            }
#pragma unroll
            for (int dh = 0; dh < 3; ++dh)
#pragma unroll
            for (int dw = 0; dw < 3; ++dw) {
                const uint4* wfp = WF
                    + ((size_t)(((dh * 3 + dw) * 4 + ciq) * 2 + kch)) * 512 + lane;
                f16x8 a[8];
#pragma unroll
                for (int cot = 0; cot < 8; ++cot)
                    a[cot] = __builtin_bit_cast(f16x8, wfp[cot * 64]);
#pragma unroll
                for (int half = 0; half < 2; ++half) {
                    uint4 braw;
                    if (dw == 1) {
                        braw = Brow[half][dh];
                    } else if (dw == 0) {
                        if (half == 0) braw = dpp4_shr(Brow[0][dh]); // lane0 -> 0 (edge)
                        else {
                            int w2 = pwh[1] - 1;                     // 15..30
                            braw = *reinterpret_cast<const uint4*>(
                                (const char*)sA + (wid + dh) * 4096 + w2 * 128
                                + (((kch * 64) | glo16) ^ ((w2 & 7) * 16)));
                        }
                    } else {
                        if (half == 1) braw = dpp4_shl(Brow[1][dh]); // lane15 -> 0 (edge)
                        else {
                            int w2 = pwh[0] + 1;                     // 1..16
                            braw = *reinterpret_cast<const uint4*>(
                                (const char*)sA + (wid + dh) * 4096 + w2 * 128
                                + (((kch * 64) | glo16) ^ ((w2 & 7) * 16)));
                        }
                    }
                    f16x8 bf = __builtin_bit_cast(f16x8, braw);
#pragma unroll
                    for (int cot = 0; cot < 8; ++cot)
                        acc[cot][half] = __builtin_amdgcn_mfma_f32_16x16x32_f16(
                            a[cot], bf, acc[cot][half], 0, 0, 0);
                }
            }
        }
    }

    unsigned* Pn = P + (size_t)n * NPAIR * PLANE;
    const int r = q4 * 4 + wid;
#pragma unroll
    for (int cot = 0; cot < 8; ++cot) {
        int cp = cot * 8 + (lane >> 4) * 2;
#pragma unroll
        for (int p = 0; p < 2; ++p) {
            int px = r * 32 + p * 16 + (lane & 15);
            unsigned u01 = q16(acc[cot][p][0]) | (q16(acc[cot][p][1]) << 16);
            unsigned u23 = q16(acc[cot][p][2]) | (q16(acc[cot][p][3]) << 16);
            Pn[cp * PLANE + px] = u01;
            Pn[(cp + 1) * PLANE + px] = u23;
        }
    }
}

// ============================================================ fallback conv
__global__ __launch_bounds__(256, 2) void conv_shift_valu(
    const float* __restrict__ in, const float* __restrict__ wgt,
    unsigned* __restrict__ out)
{
    __shared__ __align__(16) float sIn[LDS_TOT];
    const int tid  = threadIdx.x;
    const int lane = tid & 63;
    const int wid  = tid >> 6;
    const int bid  = (blockIdx.x & 7) * 128 + (blockIdx.x >> 3);
    const int n    = bid >> 4;
    const int co0  = (bid & 15) * CO_CHUNK;
    const int r    = tid >> 3;
    const int c    = tid & 7;
    const int c0   = c * 4;
    const bool cz  = (c == 0), c7 = (c == 7);

    float acc[4][CO_CHUNK];
#pragma unroll
    for (int p = 0; p < 4; ++p)
#pragma unroll
        for (int co = 0; co < CO_CHUNK; ++co) acc[p][co] = 0.0f;

    const float* inN = in + (size_t)n * CIN * PLANE;
    for (int idx = tid; idx < 512; idx += 256) {
        int slot = idx >> 6, wq = idx & 63;
        sIn[slot * LPLANE + (wq < 32 ? wq : 1024 + wq)] = 0.0f;
    }
    stage_plane4(inN + wid * PLANE, sIn + wid * LPLANE, lane);
    __syncthreads();

    int cur = 0;
    for (int ci0 = 0; ci0 < CIN; ci0 += CI_CHUNK) {
        if (ci0 + CI_CHUNK < CIN)
            stage_plane4(inN + (size_t)(ci0 + CI_CHUNK + wid) * PLANE,
                         sIn + ((cur ^ 1) * CI_CHUNK + wid) * LPLANE, lane);
        const float* sb = sIn + cur * CI_CHUNK * LPLANE;
#pragma unroll
        for (int cc = 0; cc < CI_CHUNK; ++cc) {
            float w[3][6];
#pragma unroll
            for (int dh = 0; dh < 3; ++dh) {
                const float* sp = sb + cc * LPLANE + (r + dh) * 32 + c0;
                float4 qv = *reinterpret_cast<const float4*>(sp);
                qv.x = rintf(qv.x * FSCALE) * INV_SCALE;
                qv.y = rintf(qv.y * FSCALE) * INV_SCALE;
                qv.z = rintf(qv.z * FSCALE) * INV_SCALE;
                qv.w = rintf(qv.w * FSCALE) * INV_SCALE;
                float lf = dpp_prev(qv.w);
                float rt = dpp_next(qv.x);
                w[dh][0] = cz ? 0.0f : lf;
                w[dh][1] = qv.x; w[dh][2] = qv.y; w[dh][3] = qv.z; w[dh][4] = qv.w;
                w[dh][5] = c7 ? 0.0f : rt;
            }
            const float* wp = wgt + ((size_t)co0 * CIN + (ci0 + cc)) * 9;
#pragma unroll
            for (int co = 0; co < CO_CHUNK; ++co)
#pragma unroll
                for (int dh = 0; dh < 3; ++dh)
#pragma unroll
                    for (int dw = 0; dw < 3; ++dw) {
                        const float wvv = wp[(size_t)co * CIN * 9 + dh * 3 + dw];
#pragma unroll
                        for (int p = 0; p < 4; ++p)
                            acc[p][co] = fmaf(w[dh][p + dw], wvv, acc[p][co]);
                    }
        }
        __syncthreads();
        cur ^= 1;
    }
    unsigned* outP = out + ((size_t)n * NPAIR + co0 / 2) * PLANE + r * HW + c0;
#pragma unroll
    for (int pr = 0; pr < CO_CHUNK / 2; ++pr) {
        uint4 v;
        unsigned* vp = &v.x;
#pragma unroll
        for (int p = 0; p < 4; ++p)
            vp[p] = q16(acc[p][2 * pr]) | (q16(acc[p][2 * pr + 1]) << 16);
        *reinterpret_cast<uint4*>(&outP[pr * PLANE]) = v;
    }
}

__global__ __launch_bounds__(256) void bn_relu_inplace(
    float4* __restrict__ io, const float* __restrict__ scale,
    const float* __restrict__ bias)
{
    int i = blockIdx.x * 256 + threadIdx.x;
    int c = (i >> 8) & 127;
    float sc = scale[c], bs = bias[c];
    float4 v = io[i];
    v.x = fmaxf(fmaf(v.x, sc, bs), 0.0f);
    v.y = fmaxf(fmaf(v.y, sc, bs), 0.0f);
    v.z = fmaxf(fmaf(v.z, sc, bs), 0.0f);
    v.w = fmaxf(fmaf(v.w, sc, bs), 0.0f);
    io[i] = v;
}

// ============================================================ adder (8 blk/CU)
__global__ __launch_bounds__(256, 8) void adder_packed(
    const unsigned* __restrict__ in, const unsigned* __restrict__ wq,
    float* __restrict__ out, double* __restrict__ ssum, double* __restrict__ ssq)
{
    __shared__ __align__(16) unsigned sIn[A_LDS];
    const int tid  = threadIdx.x;
    const int lane = tid & 63;
    const int wid  = tid >> 6;
    const int bid  = (blockIdx.x & 7) * 256 + (blockIdx.x >> 3);  // 2048 blocks
    const int n    = bid >> 5;
    const int co0  = (bid & 31) * A_CO;
    const int r    = tid >> 3;
    const int c    = tid & 7;
    const int c0   = c * 4;
    const bool cz  = (c == 0), c7 = (c == 7);
    const unsigned pz = PZ;

    unsigned acc[4][A_CO];
#pragma unroll
    for (int p = 0; p < 4; ++p)
#pragma unroll
        for (int co = 0; co < A_CO; ++co) acc[p][co] = 0u;

    const unsigned* inN = in + (size_t)n * NPAIR * PLANE;
    {   // guard rows of 4 plane slots: 256 entries, one per thread
        int slot = tid >> 6, wqi = tid & 63;
        sIn[slot * LPLANE + (wqi < 32 ? wqi : 1024 + wqi)] = PZ;
    }
    if (wid < A_CI)
        stage_plane4(inN + wid * PLANE, sIn + wid * LPLANE, lane);
    __syncthreads();

    int cur = 0;
    for (int s = 0; s < NPAIR / A_CI; ++s) {           // 32 steps
        if (s + 1 < NPAIR / A_CI && wid < A_CI)
            stage_plane4(inN + (size_t)((s + 1) * A_CI + wid) * PLANE,
                         sIn + ((cur ^ 1) * A_CI + wid) * LPLANE, lane);
        const unsigned* sb = sIn + cur * A_CI * LPLANE;
#pragma unroll
        for (int cc = 0; cc < A_CI; ++cc) {
            unsigned wi[3][6];
#pragma unroll
            for (int dh = 0; dh < 3; ++dh) {
                const unsigned* sp = sb + cc * LPLANE + (r + dh) * 32 + c0;
                uint4 qv = *reinterpret_cast<const uint4*>(sp);
                unsigned lf = dpp_prev_u(qv.w);
                unsigned rt = dpp_next_u(qv.x);
                wi[dh][0] = cz ? pz : lf;
                wi[dh][1] = qv.x; wi[dh][2] = qv.y; wi[dh][3] = qv.z; wi[dh][4] = qv.w;
                wi[dh][5] = c7 ? pz : rt;
            }
            const int cp = s * A_CI + cc;
            const unsigned* wrow = wq + ((size_t)co0 * NPAIR + cp) * 9;
#pragma unroll
            for (int co = 0; co < A_CO; ++co)
#pragma unroll
                for (int dh = 0; dh < 3; ++dh)
#pragma unroll
                    for (int dw = 0; dw < 3; ++dw) {
                        const unsigned wv =
                            wrow[(size_t)co * NPAIR * 9 + dh * 3 + dw];
#pragma unroll
                        for (int p = 0; p < 4; ++p)
                            asm("v_sad_u16 %0, %1, %2, %0"
                                : "+v"(acc[p][co])
                                : "v"(wi[dh][p + dw]), "s"(wv));
                    }
        }
        __syncthreads();
        cur ^= 1;
    }

    float* outP = out + ((size_t)n * COUT + co0) * PLANE + r * HW + c0;
#pragma unroll
    for (int co = 0; co < A_CO; ++co) {
        float y0 = -(float)acc[0][co] * INV_QS;
        float y1 = -(float)acc[1][co] * INV_QS;
        float y2 = -(float)acc[2][co] * INV_QS;
        float y3 = -(float)acc[3][co] * INV_QS;
        *reinterpret_cast<float4*>(&outP[co * PLANE]) = make_float4(y0, y1, y2, y3);
        float s = (y0 + y1) + (y2 + y3);
        float q = fmaf(y0, y0, y1 * y1) + fmaf(y2, y2, y3 * y3);
#pragma unroll
        for (int m = 32; m > 0; m >>= 1) {
            s += __shfl_xor(s, m, 64);
            q += __shfl_xor(q, m, 64);
        }
        if (lane == 0) {
            atomicAdd(&ssum[co0 + co], (double)s);
            atomicAdd(&ssq [co0 + co], (double)q);
        }
    }
}

// ============================================================ prep / BN
__global__ __launch_bounds__(256) void quant_pack_weights(
    const float* __restrict__ w1, const float* __restrict__ w2,
    unsigned* __restrict__ wq)
{
    int i = blockIdx.x * 256 + threadIdx.x;          // < 147456
    int layer = i >= 73728;
    int j   = i - layer * 73728;
    int co  = j / 576;
    int rem = j - co * 576;
    int cp  = rem / 9;
    int tap = rem - cp * 9;
    const float* w = layer ? w2 : w1;
    float f0 = w[((size_t)co * CIN + 2 * cp) * 9 + tap];
    float f1 = w[((size_t)co * CIN + 2 * cp + 1) * 9 + tap];
    wq[i] = q16(f0) | (q16(f1) << 16);
}

__global__ void zero_stats(double* st) {
    int i = threadIdx.x;
    st[i] = 0.0; st[i + 256] = 0.0;
}

__global__ void finalize_bn(const double* __restrict__ ssum, const double* __restrict__ ssq,
                            const float* __restrict__ gamma, const float* __restrict__ beta,
                            float* __restrict__ scale, float* __restrict__ bias)
{
    int c = threadIdx.x;  // 128
    const double cnt = (double)NB * PLANE;
    double m   = ssum[c] / cnt;
    double var = ssq[c] / cnt - m * m;
    double rstd = 1.0 / sqrt(var + 1e-5);
    float sc = (float)((double)gamma[c] * rstd);
    scale[c] = sc;
    bias[c]  = beta[c] - (float)m * sc;
}

__global__ __launch_bounds__(256) void bn_add_relu(
    float4* __restrict__ io, const float4* __restrict__ res,
    const float* __restrict__ scale, const float* __restrict__ bias)
{
    int i = blockIdx.x * 256 + threadIdx.x;
    int c = (i >> 8) & 127;
    float sc = scale[c], bs = bias[c];
    float4 v = io[i];
    float4 x = res[i];
    v.x = fmaxf(fmaf(v.x, sc, bs) + x.x, 0.0f);
    v.y = fmaxf(fmaf(v.y, sc, bs) + x.y, 0.0f);
    v.z = fmaxf(fmaf(v.z, sc, bs) + x.z, 0.0f);
    v.w = fmaxf(fmaf(v.w, sc, bs) + x.w, 0.0f);
    io[i] = v;
}

// ============================================================ launch
extern "C" void kernel_launch(void* const* d_in, const int* in_sizes, int n_in,
                              void* d_out, int out_size, void* d_ws, size_t ws_size,
                              hipStream_t stream)
{
    const float* x    = (const float*)d_in[0];
    const float* wS1  = (const float*)d_in[1];
    const float* wA1  = (const float*)d_in[2];
    const float* g1   = (const float*)d_in[3];
    const float* b1   = (const float*)d_in[4];
    const float* wS2  = (const float*)d_in[5];
    const float* wA2  = (const float*)d_in[6];
    const float* g2   = (const float*)d_in[7];
    const float* b2   = (const float*)d_in[8];
    float* outp = (float*)d_out;

    char* ws = (char*)d_ws;
    const size_t MFMA_WS = 54204416;
    const bool mf = ws_size >= MFMA_WS;

    unsigned* P = (unsigned*)ws;                    // 16,777,216 B
    double* st; float* sb; unsigned* wq; char* Gb = nullptr; unsigned* WF = nullptr;
    if (mf) {
        Gb = ws + 16777216;                         // 35,651,584 B
        st = (double*)(ws + 52428800);
        sb = (float*)(ws + 52432896);
        wq = (unsigned*)(ws + 52434944);
        WF = (unsigned*)(ws + 53024768);
    } else {
        st = (double*)(ws + 16777216);
        sb = (float*)(st + 512);
        wq = (unsigned*)(sb + 512);
    }
    double* s1 = st,       *q1 = st + 128;
    double* s2 = st + 256, *q2 = st + 384;
    float* sc1 = sb,       *bi1 = sb + 128;
    float* sc2 = sb + 256, *bi2 = sb + 384;

    const int adderGrid = NB * (COUT / A_CO);             // 2048
    const int ewGrid    = (NB * COUT * PLANE / 4) / 256;  // 8192

    zero_stats<<<1, 256, 0, stream>>>(st);
    quant_pack_weights<<<576, 256, 0, stream>>>(wA1, wA2, wq);

    if (mf) {
        wf_prep<<<1152, 256, 0, stream>>>(wS1, wS2, WF);
        transform_split<0><<<2048, 256, 0, stream>>>(x, nullptr, nullptr, (uint4*)Gb);
        conv_mfma<<<512, 256, 0, stream>>>((const uint4*)Gb, (const uint4*)WF, P);
        adder_packed<<<adderGrid, 256, 0, stream>>>(P, wq, outp, s1, q1);
        finalize_bn<<<1, 128, 0, stream>>>(s1, q1, g1, b1, sc1, bi1);
        transform_split<1><<<2048, 256, 0, stream>>>(outp, sc1, bi1, (uint4*)Gb);
        conv_mfma<<<512, 256, 0, stream>>>((const uint4*)Gb,
                                           (const uint4*)(WF + 147456), P);
        adder_packed<<<adderGrid, 256, 0, stream>>>(P, wq + 73728, outp, s2, q2);
        finalize_bn<<<1, 128, 0, stream>>>(s2, q2, g2, b2, sc2, bi2);
        bn_add_relu<<<ewGrid, 256, 0, stream>>>((float4*)outp, (const float4*)x,
                                                sc2, bi2);
    } else {
        conv_shift_valu<<<1024, 256, 0, stream>>>(x, wS1, P);
        adder_packed<<<adderGrid, 256, 0, stream>>>(P, wq, outp, s1, q1);
        finalize_bn<<<1, 128, 0, stream>>>(s1, q1, g1, b1, sc1, bi1);
        bn_relu_inplace<<<ewGrid, 256, 0, stream>>>((float4*)outp, sc1, bi1);
        conv_shift_valu<<<1024, 256, 0, stream>>>(outp, wS2, P);
        adder_packed<<<adderGrid, 256, 0, stream>>>(P, wq + 73728, outp, s2, q2);
        finalize_bn<<<1, 128, 0, stream>>>(s2, q2, g2, b2, sc2, bi2);
        bn_add_relu<<<ewGrid, 256, 0, stream>>>((float4*)outp, (const float4*)x,
                                                sc2, bi2);
    }
}